// Round 13
// baseline (11075.567 us; speedup 1.0000x reference)
//
#include <hip/hip_runtime.h>

#define FPS_N 32768
#define FPS_T 256          // threads per block
#define NBLK 8             // blocks per batch
#define PPB (FPS_N / NBLK) // 4096 points per block
#define PPT (PPB / FPS_T)  // 16 points per thread
#define NCH (PPT / 4)      // 4 four-point chunks per thread
#define NQ 256
#define DD 256
#define NT 64              // n-tile for MLP kernel
#define B_BATCH 64

// d_ws layout: gpack u64[64][256][8] (1MB) | gcxy u64 (1MB) | gcz u64 (1MB)
#define WS_PACK_U64 (B_BATCH * NQ * NBLK)
#define WS_CLEAR_BYTES (B_BATCH * NQ * NBLK * 8)   // only gpack needs zeroing

// ---------------------------------------------------------------------------
// Kernel 1: furthest point sampling, EIGHT blocks (256 thr) per batch.
// R12 lesson: compute is 0.16us/iter but the iteration took 2.0us — the
// serial combine chain (shuffle reduce -> LDS -> barrier -> re-reduce ->
// store -> poll -> butterfly -> centroid GATHER -> LDS broadcast -> barrier)
// was the floor. This version is BARRIER-FREE and GATHER-FREE:
//  - wave butterfly on packed u64 (distbits<<32|~idx; monotone, first-occ.)
//  - lane0 release-stores wave max to per-round LDS slot; all threads
//    acquire-poll the 4 slots (no __syncthreads)
//  - the unique block-winner THREAD (own pack == block max) extracts its
//    point's coords via static predicated pass and stores coords+pack to
//    the global slot -> winner coords RIDE WITH the result (no gather)
//  - lanes 0-7 of EVERY wave poll the 8-slot 64B line, butterfly carrying
//    (pack,x,y,z), readfirstlane broadcast -> each wave self-serves.
// Per-round slots (LDS[256][4], ws 3MB) -> deterministic replays; pack!=0
// always (~idx >= 0xFFFF8000). 512 blocks x <=128 VGPR = exactly 2/CU
// co-resident -> no deadlock; store-before-poll.
// Arithmetic matches numpy bitwise: sub, mul, add (no FMA), fminf.
// ---------------------------------------------------------------------------
__global__ __attribute__((amdgpu_flat_work_group_size(FPS_T, FPS_T),
                          amdgpu_waves_per_eu(2, 2)))
void fps_kernel(const float* __restrict__ xyz, float* __restrict__ qout,
                unsigned long long* __restrict__ gpack,
                unsigned long long* __restrict__ gcxy,
                unsigned long long* __restrict__ gcz) {
  const int gid = blockIdx.x;
  const int xcd = gid & 7;          // round-robin dispatch: block i -> XCD i%8
  const int s = gid >> 3;
  const int b = xcd + 8 * (s >> 3); // all 8 eighths of batch b on same XCD
  const int q = s & 7;
  const int t = threadIdx.x;
  const int w = t >> 6;             // wave id 0..3
  const int lane = t & 63;

  const float* __restrict__ base = xyz + (size_t)b * (FPS_N * 3);
  const float4* __restrict__ base4 =
      (const float4*)(base + (size_t)q * PPB * 3) + (size_t)t * (PPT * 3 / 4);
  float* qb = qout + (size_t)b * (NQ * 3);
  unsigned long long* bpack = gpack + (size_t)b * (NQ * NBLK);
  unsigned long long* bcxy = gcxy + (size_t)b * (NQ * NBLK);
  unsigned long long* bcz = gcz + (size_t)b * (NQ * NBLK);

  __shared__ unsigned long long spack[NQ][4];   // 8KB: per-round per-wave slots

  // zero-init LDS slots (once; per-round slots need no reset/parity)
  for (int i = t; i < NQ * 4; i += FPS_T) ((unsigned long long*)spack)[i] = 0ull;

  // persistent registers: coords 12 float4 = 48 VGPR, dist 4 float4 = 16 VGPR
  float4 C[PPT * 3 / 4];
#pragma unroll
  for (int i = 0; i < PPT * 3 / 4; ++i) C[i] = base4[i];
#pragma unroll
  for (int i = 0; i < PPT * 3 / 4; ++i) {   // pin: forbid remat
    asm volatile("" : "+v"(C[i].x), "+v"(C[i].y), "+v"(C[i].z), "+v"(C[i].w));
  }
  float4 Dst[NCH];
#pragma unroll
  for (int c = 0; c < NCH; ++c) Dst[c] = make_float4(1e10f, 1e10f, 1e10f, 1e10f);

  __syncthreads();   // LDS init visible (the only barrier in the kernel)

  if (q == 0 && t == 0) { qb[0] = base[0]; qb[1] = base[1]; qb[2] = base[2]; }
  float cx = base[0], cy = base[1], cz = base[2];   // inds[0] == 0

#pragma unroll 1
  for (int j = 1; j < NQ; ++j) {
    float best = -1.0f;
    int bik = 0;

#pragma unroll
    for (int c = 0; c < NCH; ++c) {
      const float4 a4 = C[3 * c + 0];
      const float4 b4 = C[3 * c + 1];
      const float4 c4 = C[3 * c + 2];
      // unpack 12 floats -> 4 points (register renaming, no real ops)
      const float px[4] = {a4.x, a4.w, b4.z, c4.y};
      const float py[4] = {a4.y, b4.x, b4.w, c4.z};
      const float pz[4] = {a4.z, b4.y, c4.x, c4.w};
      const float dold[4] = {Dst[c].x, Dst[c].y, Dst[c].z, Dst[c].w};
      float dnew[4];
#pragma unroll
      for (int i = 0; i < 4; ++i) {
        const float dx = __fsub_rn(px[i], cx);
        const float dy = __fsub_rn(py[i], cy);
        const float dz = __fsub_rn(pz[i], cz);
        // numpy order: (dx^2 + dy^2) + dz^2, no fma
        const float d = __fadd_rn(__fadd_rn(__fmul_rn(dx, dx), __fmul_rn(dy, dy)),
                                  __fmul_rn(dz, dz));
        const float nd = fminf(dold[i], d);
        dnew[i] = nd;
        if (nd > best) { best = nd; bik = c * 4 + i; }  // strict >: first occ.
      }
      Dst[c] = make_float4(dnew[0], dnew[1], dnew[2], dnew[3]);
    }
    const int bi = q * PPB + t * PPT + bik;   // global point index
    // pack: monotone in dist (f32>=0); ~idx -> max picks smallest index; never 0
    const unsigned long long mypack =
        ((unsigned long long)(unsigned int)__float_as_int(best) << 32) |
        (unsigned int)~(unsigned int)bi;

    // wave (64-lane) max reduce on pack
    unsigned long long wmax = mypack;
#pragma unroll
    for (int off = 32; off; off >>= 1) {
      const unsigned long long o = __shfl_xor(wmax, off);
      if (o > wmax) wmax = o;
    }
    if (lane == 0) {
      __hip_atomic_store(&spack[j][w], wmax, __ATOMIC_RELEASE,
                         __HIP_MEMORY_SCOPE_WORKGROUP);
    }

    // LDS poll: all threads wait for the 4 wave slots (broadcast reads)
    unsigned long long s0, s1, s2, s3;
    do {
      s0 = __hip_atomic_load(&spack[j][0], __ATOMIC_ACQUIRE, __HIP_MEMORY_SCOPE_WORKGROUP);
      s1 = __hip_atomic_load(&spack[j][1], __ATOMIC_ACQUIRE, __HIP_MEMORY_SCOPE_WORKGROUP);
      s2 = __hip_atomic_load(&spack[j][2], __ATOMIC_ACQUIRE, __HIP_MEMORY_SCOPE_WORKGROUP);
      s3 = __hip_atomic_load(&spack[j][3], __ATOMIC_ACQUIRE, __HIP_MEMORY_SCOPE_WORKGROUP);
    } while ((s0 == 0ull) | (s1 == 0ull) | (s2 == 0ull) | (s3 == 0ull));
    unsigned long long bmax = s0;
    if (s1 > bmax) bmax = s1;
    if (s2 > bmax) bmax = s2;
    if (s3 > bmax) bmax = s3;

    // unique block-winner thread: extract coords (static idx) + global store
    if (mypack == bmax) {
      float wx = 0.f, wy = 0.f, wz = 0.f;
#pragma unroll
      for (int c = 0; c < NCH; ++c) {
        const float4 a4 = C[3 * c + 0];
        const float4 b4 = C[3 * c + 1];
        const float4 c4 = C[3 * c + 2];
        const float px[4] = {a4.x, a4.w, b4.z, c4.y};
        const float py[4] = {a4.y, b4.x, b4.w, c4.z};
        const float pz[4] = {a4.z, b4.y, c4.x, c4.w};
#pragma unroll
        for (int i = 0; i < 4; ++i) {
          if (c * 4 + i == bik) { wx = px[i]; wy = py[i]; wz = pz[i]; }
        }
      }
      const int gi = j * NBLK + q;
      __hip_atomic_store(&bcxy[gi],
                         ((unsigned long long)__float_as_uint(wy) << 32) |
                             __float_as_uint(wx),
                         __ATOMIC_RELAXED, __HIP_MEMORY_SCOPE_AGENT);
      __hip_atomic_store(&bcz[gi], (unsigned long long)__float_as_uint(wz),
                         __ATOMIC_RELAXED, __HIP_MEMORY_SCOPE_AGENT);
      __hip_atomic_store(&bpack[gi], bmax, __ATOMIC_RELEASE,
                         __HIP_MEMORY_SCOPE_AGENT);   // pack last: coords ride ahead
    }

    // global combine: lanes 0-7 of EVERY wave poll + butterfly with coords
    unsigned long long p = 0, pxy = 0, pzz = 0;
    if (lane < 8) {
      do {
        p = __hip_atomic_load(&bpack[j * NBLK + lane], __ATOMIC_ACQUIRE,
                              __HIP_MEMORY_SCOPE_AGENT);
      } while (__any(p == 0ull));
      pxy = __hip_atomic_load(&bcxy[j * NBLK + lane], __ATOMIC_RELAXED,
                              __HIP_MEMORY_SCOPE_AGENT);
      pzz = __hip_atomic_load(&bcz[j * NBLK + lane], __ATOMIC_RELAXED,
                              __HIP_MEMORY_SCOPE_AGENT);
#pragma unroll
      for (int off = 1; off < NBLK; off <<= 1) {
        const unsigned long long op = __shfl_xor(p, off);
        const unsigned long long oxy = __shfl_xor(pxy, off);
        const unsigned long long oz = __shfl_xor(pzz, off);
        if (op > p) { p = op; pxy = oxy; pzz = oz; }
      }
    }
    // broadcast lane 0's winner coords to the whole wave
    cx = __uint_as_float(__builtin_amdgcn_readfirstlane((unsigned int)(pxy & 0xffffffffull)));
    cy = __uint_as_float(__builtin_amdgcn_readfirstlane((unsigned int)(pxy >> 32)));
    cz = __uint_as_float(__builtin_amdgcn_readfirstlane((unsigned int)(pzz & 0xffffffffull)));

    if (q == 0 && t == 0) {
      qb[3 * j + 0] = cx; qb[3 * j + 1] = cy; qb[3 * j + 2] = cz;
    }
  }
}

// ---------------------------------------------------------------------------
// Kernel 2: fourier positional embedding + 2-layer MLP, fused. (unchanged)
// ---------------------------------------------------------------------------
__global__ __launch_bounds__(256) void embed_mlp_kernel(
    const float* __restrict__ qxyz, const float* __restrict__ pcmin,
    const float* __restrict__ pcmax, const float* __restrict__ G,
    const float* __restrict__ W1, const float* __restrict__ b1,
    const float* __restrict__ W2, const float* __restrict__ b2,
    float* __restrict__ out) {
  const int b = blockIdx.x >> 2;
  const int n0 = (blockIdx.x & 3) * NT;
  const int tid = threadIdx.x;
  const int ty = tid >> 4, tx = tid & 15;

  __shared__ __align__(16) float P[DD][NT + 4];   // pos
  __shared__ __align__(16) float H[DD][NT + 4];   // hidden
  __shared__ __align__(16) float Wl[64][NT + 4];  // W tile (transposed)
  __shared__ float snorm[NT][3];

  if (tid < NT) {
    const int n = n0 + tid;
    const float qx = qxyz[(size_t)b * (NQ * 3) + 3 * n + 0];
    const float qy = qxyz[(size_t)b * (NQ * 3) + 3 * n + 1];
    const float qz = qxyz[(size_t)b * (NQ * 3) + 3 * n + 2];
    snorm[tid][0] = (qx - pcmin[3 * b + 0]) / (pcmax[3 * b + 0] - pcmin[3 * b + 0]);
    snorm[tid][1] = (qy - pcmin[3 * b + 1]) / (pcmax[3 * b + 1] - pcmin[3 * b + 1]);
    snorm[tid][2] = (qz - pcmin[3 * b + 2]) / (pcmax[3 * b + 2] - pcmin[3 * b + 2]);
  }
  __syncthreads();

  {
    const int nn = tid & 63;
    const int fg = tid >> 6;   // 0..3
    const float nx = snorm[nn][0], ny = snorm[nn][1], nz = snorm[nn][2];
#pragma unroll 4
    for (int ff = 0; ff < 32; ++ff) {
      const int f = fg * 32 + ff;
      const float s = nx * G[f] + ny * G[128 + f] + nz * G[256 + f];
      const float proj = 6.28318530717958647692f * s;
      P[f][nn] = sinf(proj);
      P[f + 128][nn] = cosf(proj);
    }
  }

  for (int layer = 0; layer < 2; ++layer) {
    const float* W = layer ? W2 : W1;
    const float* bias = layer ? b2 : b1;
    const float (*src)[NT + 4] = layer ? H : P;

    for (int dt = 0; dt < 4; ++dt) {
      float acc[4][4] = {};
      for (int kt = 0; kt < 4; ++kt) {
        __syncthreads();
        {  // stage W tile transposed: Wl[c][d] = W[dt*64+d][kt*64+c]
          const int r = tid >> 2;
          const int cb = (tid & 3) * 16;
          const float* wrow = W + (size_t)(dt * 64 + r) * DD + kt * 64 + cb;
#pragma unroll
          for (int i = 0; i < 4; ++i) {
            const float4 v = *(const float4*)(wrow + 4 * i);
            Wl[cb + 4 * i + 0][r] = v.x;
            Wl[cb + 4 * i + 1][r] = v.y;
            Wl[cb + 4 * i + 2][r] = v.z;
            Wl[cb + 4 * i + 3][r] = v.w;
          }
        }
        __syncthreads();
#pragma unroll 8
        for (int cc = 0; cc < 64; ++cc) {
          const float4 a = *(const float4*)&Wl[cc][ty * 4];
          const float4 p4 = *(const float4*)&src[kt * 64 + cc][tx * 4];
          acc[0][0] = fmaf(a.x, p4.x, acc[0][0]);
          acc[0][1] = fmaf(a.x, p4.y, acc[0][1]);
          acc[0][2] = fmaf(a.x, p4.z, acc[0][2]);
          acc[0][3] = fmaf(a.x, p4.w, acc[0][3]);
          acc[1][0] = fmaf(a.y, p4.x, acc[1][0]);
          acc[1][1] = fmaf(a.y, p4.y, acc[1][1]);
          acc[1][2] = fmaf(a.y, p4.z, acc[1][2]);
          acc[1][3] = fmaf(a.y, p4.w, acc[1][3]);
          acc[2][0] = fmaf(a.z, p4.x, acc[2][0]);
          acc[2][1] = fmaf(a.z, p4.y, acc[2][1]);
          acc[2][2] = fmaf(a.z, p4.z, acc[2][2]);
          acc[2][3] = fmaf(a.z, p4.w, acc[2][3]);
          acc[3][0] = fmaf(a.w, p4.x, acc[3][0]);
          acc[3][1] = fmaf(a.w, p4.y, acc[3][1]);
          acc[3][2] = fmaf(a.w, p4.z, acc[3][2]);
          acc[3][3] = fmaf(a.w, p4.w, acc[3][3]);
        }
      }
      if (layer == 0) {
#pragma unroll
        for (int i = 0; i < 4; ++i) {
          const float bv = bias[dt * 64 + ty * 4 + i];
          float4 h;
          h.x = fmaxf(acc[i][0] + bv, 0.f);
          h.y = fmaxf(acc[i][1] + bv, 0.f);
          h.z = fmaxf(acc[i][2] + bv, 0.f);
          h.w = fmaxf(acc[i][3] + bv, 0.f);
          *(float4*)&H[dt * 64 + ty * 4 + i][tx * 4] = h;
        }
      } else {
        float* ob = out + (size_t)b * (DD * NQ);
#pragma unroll
        for (int i = 0; i < 4; ++i) {
          const float bv = bias[dt * 64 + ty * 4 + i];
          float4 h;
          h.x = fmaxf(acc[i][0] + bv, 0.f);
          h.y = fmaxf(acc[i][1] + bv, 0.f);
          h.z = fmaxf(acc[i][2] + bv, 0.f);
          h.w = fmaxf(acc[i][3] + bv, 0.f);
          *(float4*)(ob + (size_t)(dt * 64 + ty * 4 + i) * NQ + n0 + tx * 4) = h;
        }
      }
    }
  }
}

extern "C" void kernel_launch(void* const* d_in, const int* in_sizes, int n_in,
                              void* d_out, int out_size, void* d_ws, size_t ws_size,
                              hipStream_t stream) {
  (void)in_sizes; (void)n_in; (void)ws_size; (void)out_size;
  const float* xyz   = (const float*)d_in[0];
  const float* pcmin = (const float*)d_in[1];
  const float* pcmax = (const float*)d_in[2];
  const float* G     = (const float*)d_in[3];
  const float* W1    = (const float*)d_in[4];
  const float* b1    = (const float*)d_in[5];
  const float* W2    = (const float*)d_in[6];
  const float* b2    = (const float*)d_in[7];

  float* qxyz  = (float*)d_out;                       // [64][256][3]
  float* embed = qxyz + (size_t)B_BATCH * NQ * 3;     // [64][256][256]

  unsigned long long* gpack = (unsigned long long*)d_ws;
  unsigned long long* gcxy = gpack + WS_PACK_U64;
  unsigned long long* gcz = gcxy + WS_PACK_U64;

  // clear pack slots every launch (deterministic across graph replays)
  hipMemsetAsync(d_ws, 0, WS_CLEAR_BYTES, stream);

  hipLaunchKernelGGL(fps_kernel, dim3(B_BATCH * NBLK), dim3(FPS_T), 0, stream,
                     xyz, qxyz, gpack, gcxy, gcz);
  hipLaunchKernelGGL(embed_mlp_kernel, dim3(B_BATCH * 4), dim3(256), 0, stream,
                     qxyz, pcmin, pcmax, G, W1, b1, W2, b2, embed);
}

// Round 14
// 758.960 us; speedup vs baseline: 14.5931x; 14.5931x over previous
//
#include <hip/hip_runtime.h>

#define FPS_N 32768
#define FPS_T 256          // threads per block
#define NBLK 8             // blocks per batch
#define PPB (FPS_N / NBLK) // 4096 points per block
#define PPT (PPB / FPS_T)  // 16 points per thread
#define NCH (PPT / 4)      // 4 four-point chunks per thread
#define NQ 256
#define DD 256
#define NT 64              // n-tile for MLP kernel
#define B_BATCH 64

// d_ws: u64 slot[64][256][8][3] = 3 MB, memset 0xFF per launch (sentinel)
#define WS_CLEAR_BYTES (B_BATCH * NQ * NBLK * 3 * 8)
#define SENT 0xffffffffffffffffull

// ---------------------------------------------------------------------------
// Kernel 1: furthest point sampling, EIGHT blocks (256 thr) per batch.
// R13 lesson: all-wave global ACQUIRE polling = L2 storm (11ms). Polls must
// be FEW lanes + RELAXED (R12 structure, 2.0us/iter). This round keeps the
// R12 skeleton and shortens its chain:
//  (a) coords RIDE with the result: lanes pre-extract their best point's
//      coords (static cndmask), wave butterfly carries (pack,xy,z); t0
//      stores 3 self-validating u64 slots (sentinel=0xFF..FF: valid pack
//      has finite-f32 distbits, coords are never NaN-all-ones, z high=0)
//      -> all RELAXED, no release/acquire, no centroid gather.
//  (b) parallel poll: wave0 lanes 0-23 poll one u64 each (one L2 latency),
//      shfl-gather to lanes 0-7, 3-step butterfly w/ coords, LDS bc, barrier.
// pack = distbits<<32 | ~idx (monotone for f32>=0; ~idx = smallest index on
// ties = jnp.argmax first-occurrence). Arithmetic matches numpy bitwise.
// 512 blocks x ~128 VGPR = 2 blocks/CU co-resident -> deadlock-free.
// ---------------------------------------------------------------------------
__global__ __attribute__((amdgpu_flat_work_group_size(FPS_T, FPS_T),
                          amdgpu_waves_per_eu(2, 2)))
void fps_kernel(const float* __restrict__ xyz, float* __restrict__ qout,
                unsigned long long* __restrict__ gslot) {
  const int gid = blockIdx.x;
  const int xcd = gid & 7;          // round-robin dispatch: block i -> XCD i%8
  const int s = gid >> 3;
  const int b = xcd + 8 * (s >> 3); // all 8 eighths of batch b on same XCD
  const int q = s & 7;
  const int t = threadIdx.x;
  const int w = t >> 6;             // wave id 0..3
  const int lane = t & 63;

  const float* __restrict__ base = xyz + (size_t)b * (FPS_N * 3);
  const float4* __restrict__ base4 =
      (const float4*)(base + (size_t)q * PPB * 3) + (size_t)t * (PPT * 3 / 4);
  float* qb = qout + (size_t)b * (NQ * 3);
  unsigned long long* bslot = gslot + ((size_t)b * NQ) * (NBLK * 3);

  __shared__ unsigned long long redp[FPS_T / 64], redxy[FPS_T / 64];
  __shared__ float redz[FPS_T / 64];
  __shared__ float4 bc;   // broadcast: cx, cy, cz

  // persistent registers: coords 12 float4 = 48 VGPR, dist 4 float4 = 16 VGPR
  float4 C[PPT * 3 / 4];
#pragma unroll
  for (int i = 0; i < PPT * 3 / 4; ++i) C[i] = base4[i];
#pragma unroll
  for (int i = 0; i < PPT * 3 / 4; ++i) {   // pin: forbid remat
    asm volatile("" : "+v"(C[i].x), "+v"(C[i].y), "+v"(C[i].z), "+v"(C[i].w));
  }
  float4 Dst[NCH];
#pragma unroll
  for (int c = 0; c < NCH; ++c) Dst[c] = make_float4(1e10f, 1e10f, 1e10f, 1e10f);

  if (q == 0 && t == 0) { qb[0] = base[0]; qb[1] = base[1]; qb[2] = base[2]; }
  float cx = base[0], cy = base[1], cz = base[2];   // inds[0] == 0

#pragma unroll 1
  for (int j = 1; j < NQ; ++j) {
    float best = -1.0f;
    int bik = 0;

#pragma unroll
    for (int c = 0; c < NCH; ++c) {
      const float4 a4 = C[3 * c + 0];
      const float4 b4 = C[3 * c + 1];
      const float4 c4 = C[3 * c + 2];
      // unpack 12 floats -> 4 points (register renaming, no real ops)
      const float px[4] = {a4.x, a4.w, b4.z, c4.y};
      const float py[4] = {a4.y, b4.x, b4.w, c4.z};
      const float pz[4] = {a4.z, b4.y, c4.x, c4.w};
      const float dold[4] = {Dst[c].x, Dst[c].y, Dst[c].z, Dst[c].w};
      float dnew[4];
#pragma unroll
      for (int i = 0; i < 4; ++i) {
        const float dx = __fsub_rn(px[i], cx);
        const float dy = __fsub_rn(py[i], cy);
        const float dz = __fsub_rn(pz[i], cz);
        // numpy order: (dx^2 + dy^2) + dz^2, no fma
        const float d = __fadd_rn(__fadd_rn(__fmul_rn(dx, dx), __fmul_rn(dy, dy)),
                                  __fmul_rn(dz, dz));
        const float nd = fminf(dold[i], d);
        dnew[i] = nd;
        if (nd > best) { best = nd; bik = c * 4 + i; }  // strict >: first occ.
      }
      Dst[c] = make_float4(dnew[0], dnew[1], dnew[2], dnew[3]);
    }
    const int bi = q * PPB + t * PPT + bik;   // global point index
    unsigned long long p =
        ((unsigned long long)(unsigned int)__float_as_int(best) << 32) |
        (unsigned int)~(unsigned int)bi;

    // extract own best point's coords (static predicated selects)
    float wx = 0.f, wy = 0.f, wz = 0.f;
#pragma unroll
    for (int c = 0; c < NCH; ++c) {
      const float4 a4 = C[3 * c + 0];
      const float4 b4 = C[3 * c + 1];
      const float4 c4 = C[3 * c + 2];
      const float px[4] = {a4.x, a4.w, b4.z, c4.y};
      const float py[4] = {a4.y, b4.x, b4.w, c4.z};
      const float pz[4] = {a4.z, b4.y, c4.x, c4.w};
#pragma unroll
      for (int i = 0; i < 4; ++i) {
        if (c * 4 + i == bik) { wx = px[i]; wy = py[i]; wz = pz[i]; }
      }
    }
    unsigned long long pxy = ((unsigned long long)__float_as_uint(wy) << 32) |
                             __float_as_uint(wx);
    float pz2 = wz;

    // wave (64-lane) butterfly max on pack, carrying coords
#pragma unroll
    for (int off = 32; off; off >>= 1) {
      const unsigned long long op = __shfl_xor(p, off);
      const unsigned long long oxy = __shfl_xor(pxy, off);
      const float oz = __shfl_xor(pz2, off);
      if (op > p) { p = op; pxy = oxy; pz2 = oz; }
    }
    if (lane == 0) { redp[w] = p; redxy[w] = pxy; redz[w] = pz2; }
    __syncthreads();

    if (w == 0) {
      // cross-wave reduce in lanes 0-3
      if (lane < 4) {
        p = redp[lane]; pxy = redxy[lane]; pz2 = redz[lane];
#pragma unroll
        for (int off = 1; off < 4; off <<= 1) {
          const unsigned long long op = __shfl_xor(p, off);
          const unsigned long long oxy = __shfl_xor(pxy, off);
          const float oz = __shfl_xor(pz2, off);
          if (op > p) { p = op; pxy = oxy; pz2 = oz; }
        }
      }
      // t0 publishes block result: 3 self-validating relaxed u64 stores
      if (lane == 0) {
        unsigned long long* sl = bslot + (size_t)j * (NBLK * 3) + q * 3;
        __hip_atomic_store(&sl[0], p, __ATOMIC_RELAXED, __HIP_MEMORY_SCOPE_AGENT);
        __hip_atomic_store(&sl[1], pxy, __ATOMIC_RELAXED, __HIP_MEMORY_SCOPE_AGENT);
        __hip_atomic_store(&sl[2], (unsigned long long)__float_as_uint(pz2),
                           __ATOMIC_RELAXED, __HIP_MEMORY_SCOPE_AGENT);
      }
      // parallel poll: lanes 0-23 each own one u64 of the 24-slot line
      unsigned long long own = 0;
      if (lane < NBLK * 3) {
        const unsigned long long* sl = bslot + (size_t)j * (NBLK * 3) + lane;
        do {
          own = __hip_atomic_load(sl, __ATOMIC_RELAXED, __HIP_MEMORY_SCOPE_AGENT);
        } while (own == SENT);
      }
      // gather (pack,xy,z) of slot q into lane q (q<8)
      const int l3 = lane * 3;
      const unsigned long long gp = __shfl(own, l3);
      const unsigned long long gxy = __shfl(own, l3 + 1);
      const unsigned long long gz = __shfl(own, l3 + 2);
      p = gp; pxy = gxy; pz2 = __uint_as_float((unsigned int)gz);
      // butterfly over the 8 block results (lanes 0-7)
#pragma unroll
      for (int off = 1; off < NBLK; off <<= 1) {
        const unsigned long long op = __shfl_xor(p, off);
        const unsigned long long oxy = __shfl_xor(pxy, off);
        const float oz = __shfl_xor(pz2, off);
        if (op > p) { p = op; pxy = oxy; pz2 = oz; }
      }
      if (lane == 0) {
        const float ncx = __uint_as_float((unsigned int)(pxy & 0xffffffffull));
        const float ncy = __uint_as_float((unsigned int)(pxy >> 32));
        bc = make_float4(ncx, ncy, pz2, 0.f);
        if (q == 0) { qb[3 * j + 0] = ncx; qb[3 * j + 1] = ncy; qb[3 * j + 2] = pz2; }
      }
    }
    __syncthreads();
    cx = bc.x; cy = bc.y; cz = bc.z;
  }
}

// ---------------------------------------------------------------------------
// Kernel 2: fourier positional embedding + 2-layer MLP, fused. (unchanged)
// ---------------------------------------------------------------------------
__global__ __launch_bounds__(256) void embed_mlp_kernel(
    const float* __restrict__ qxyz, const float* __restrict__ pcmin,
    const float* __restrict__ pcmax, const float* __restrict__ G,
    const float* __restrict__ W1, const float* __restrict__ b1,
    const float* __restrict__ W2, const float* __restrict__ b2,
    float* __restrict__ out) {
  const int b = blockIdx.x >> 2;
  const int n0 = (blockIdx.x & 3) * NT;
  const int tid = threadIdx.x;
  const int ty = tid >> 4, tx = tid & 15;

  __shared__ __align__(16) float P[DD][NT + 4];   // pos
  __shared__ __align__(16) float H[DD][NT + 4];   // hidden
  __shared__ __align__(16) float Wl[64][NT + 4];  // W tile (transposed)
  __shared__ float snorm[NT][3];

  if (tid < NT) {
    const int n = n0 + tid;
    const float qx = qxyz[(size_t)b * (NQ * 3) + 3 * n + 0];
    const float qy = qxyz[(size_t)b * (NQ * 3) + 3 * n + 1];
    const float qz = qxyz[(size_t)b * (NQ * 3) + 3 * n + 2];
    snorm[tid][0] = (qx - pcmin[3 * b + 0]) / (pcmax[3 * b + 0] - pcmin[3 * b + 0]);
    snorm[tid][1] = (qy - pcmin[3 * b + 1]) / (pcmax[3 * b + 1] - pcmin[3 * b + 1]);
    snorm[tid][2] = (qz - pcmin[3 * b + 2]) / (pcmax[3 * b + 2] - pcmin[3 * b + 2]);
  }
  __syncthreads();

  {
    const int nn = tid & 63;
    const int fg = tid >> 6;   // 0..3
    const float nx = snorm[nn][0], ny = snorm[nn][1], nz = snorm[nn][2];
#pragma unroll 4
    for (int ff = 0; ff < 32; ++ff) {
      const int f = fg * 32 + ff;
      const float s = nx * G[f] + ny * G[128 + f] + nz * G[256 + f];
      const float proj = 6.28318530717958647692f * s;
      P[f][nn] = sinf(proj);
      P[f + 128][nn] = cosf(proj);
    }
  }

  for (int layer = 0; layer < 2; ++layer) {
    const float* W = layer ? W2 : W1;
    const float* bias = layer ? b2 : b1;
    const float (*src)[NT + 4] = layer ? H : P;

    for (int dt = 0; dt < 4; ++dt) {
      float acc[4][4] = {};
      for (int kt = 0; kt < 4; ++kt) {
        __syncthreads();
        {  // stage W tile transposed: Wl[c][d] = W[dt*64+d][kt*64+c]
          const int r = tid >> 2;
          const int cb = (tid & 3) * 16;
          const float* wrow = W + (size_t)(dt * 64 + r) * DD + kt * 64 + cb;
#pragma unroll
          for (int i = 0; i < 4; ++i) {
            const float4 v = *(const float4*)(wrow + 4 * i);
            Wl[cb + 4 * i + 0][r] = v.x;
            Wl[cb + 4 * i + 1][r] = v.y;
            Wl[cb + 4 * i + 2][r] = v.z;
            Wl[cb + 4 * i + 3][r] = v.w;
          }
        }
        __syncthreads();
#pragma unroll 8
        for (int cc = 0; cc < 64; ++cc) {
          const float4 a = *(const float4*)&Wl[cc][ty * 4];
          const float4 p4 = *(const float4*)&src[kt * 64 + cc][tx * 4];
          acc[0][0] = fmaf(a.x, p4.x, acc[0][0]);
          acc[0][1] = fmaf(a.x, p4.y, acc[0][1]);
          acc[0][2] = fmaf(a.x, p4.z, acc[0][2]);
          acc[0][3] = fmaf(a.x, p4.w, acc[0][3]);
          acc[1][0] = fmaf(a.y, p4.x, acc[1][0]);
          acc[1][1] = fmaf(a.y, p4.y, acc[1][1]);
          acc[1][2] = fmaf(a.y, p4.z, acc[1][2]);
          acc[1][3] = fmaf(a.y, p4.w, acc[1][3]);
          acc[2][0] = fmaf(a.z, p4.x, acc[2][0]);
          acc[2][1] = fmaf(a.z, p4.y, acc[2][1]);
          acc[2][2] = fmaf(a.z, p4.z, acc[2][2]);
          acc[2][3] = fmaf(a.z, p4.w, acc[2][3]);
          acc[3][0] = fmaf(a.w, p4.x, acc[3][0]);
          acc[3][1] = fmaf(a.w, p4.y, acc[3][1]);
          acc[3][2] = fmaf(a.w, p4.z, acc[3][2]);
          acc[3][3] = fmaf(a.w, p4.w, acc[3][3]);
        }
      }
      if (layer == 0) {
#pragma unroll
        for (int i = 0; i < 4; ++i) {
          const float bv = bias[dt * 64 + ty * 4 + i];
          float4 h;
          h.x = fmaxf(acc[i][0] + bv, 0.f);
          h.y = fmaxf(acc[i][1] + bv, 0.f);
          h.z = fmaxf(acc[i][2] + bv, 0.f);
          h.w = fmaxf(acc[i][3] + bv, 0.f);
          *(float4*)&H[dt * 64 + ty * 4 + i][tx * 4] = h;
        }
      } else {
        float* ob = out + (size_t)b * (DD * NQ);
#pragma unroll
        for (int i = 0; i < 4; ++i) {
          const float bv = bias[dt * 64 + ty * 4 + i];
          float4 h;
          h.x = fmaxf(acc[i][0] + bv, 0.f);
          h.y = fmaxf(acc[i][1] + bv, 0.f);
          h.z = fmaxf(acc[i][2] + bv, 0.f);
          h.w = fmaxf(acc[i][3] + bv, 0.f);
          *(float4*)(ob + (size_t)(dt * 64 + ty * 4 + i) * NQ + n0 + tx * 4) = h;
        }
      }
    }
  }
}

extern "C" void kernel_launch(void* const* d_in, const int* in_sizes, int n_in,
                              void* d_out, int out_size, void* d_ws, size_t ws_size,
                              hipStream_t stream) {
  (void)in_sizes; (void)n_in; (void)ws_size; (void)out_size;
  const float* xyz   = (const float*)d_in[0];
  const float* pcmin = (const float*)d_in[1];
  const float* pcmax = (const float*)d_in[2];
  const float* G     = (const float*)d_in[3];
  const float* W1    = (const float*)d_in[4];
  const float* b1    = (const float*)d_in[5];
  const float* W2    = (const float*)d_in[6];
  const float* b2    = (const float*)d_in[7];

  float* qxyz  = (float*)d_out;                       // [64][256][3]
  float* embed = qxyz + (size_t)B_BATCH * NQ * 3;     // [64][256][256]

  unsigned long long* gslot = (unsigned long long*)d_ws;

  // sentinel-fill slots every launch (deterministic across graph replays)
  hipMemsetAsync(d_ws, 0xFF, WS_CLEAR_BYTES, stream);

  hipLaunchKernelGGL(fps_kernel, dim3(B_BATCH * NBLK), dim3(FPS_T), 0, stream,
                     xyz, qxyz, gslot);
  hipLaunchKernelGGL(embed_mlp_kernel, dim3(B_BATCH * 4), dim3(256), 0, stream,
                     qxyz, pcmin, pcmax, G, W1, b1, W2, b2, embed);
}

// Round 15
// 677.362 us; speedup vs baseline: 16.3510x; 1.1205x over previous
//
#include <hip/hip_runtime.h>

#define FPS_N 32768
#define FPS_T 256          // threads per block
#define NBLK 8             // blocks per batch
#define PPB (FPS_N / NBLK) // 4096 points per block
#define PPT (PPB / FPS_T)  // 16 points per thread
#define NCH (PPT / 4)      // 4 four-point chunks per thread
#define NQ 256
#define DD 256
#define NT 64              // n-tile for MLP kernel
#define B_BATCH 64

// d_ws: u64 slot[64][256][8] = 1 MB, memset 0xFF per launch (sentinel)
#define WS_CLEAR_BYTES (B_BATCH * NQ * NBLK * 8)
#define SENT 0xffffffffffffffffull

// ---------------------------------------------------------------------------
// Kernel 1: furthest point sampling, EIGHT blocks (256 thr) per batch.
// Best skeleton = R12 (505us). Its defect: wave0 did the whole global
// combine serially while 3 waves idled through a 2nd barrier + LDS bc.
// This version: ONE barrier/iter, then EVERY wave self-serves:
//   wave butterfly (pack u64) -> lane0 -> LDS partial (parity dbuf)
//   -> barrier -> each wave: read 4 partials, 2-step bf = block max
//   -> wave0-lane0 publishes ONE u64 slot (relaxed; self-validating vs
//      0xFF sentinel: distbits of finite f32>=0 never 0xFFFFFFFF)
//   -> lanes 0-7 of every wave relaxed-poll the 8-u64 line (64B),
//      3-step bf, readfirstlane winner idx, uniform-address centroid
//      gather from base (one broadcast L2 request per wave).
// R13 lesson respected: polls are few-lane + RELAXED (no acquire storm).
// pack = distbits<<32 | ~idx (monotone f32>=0; ~idx = smallest index on
// ties = jnp.argmax first-occurrence). Arithmetic matches numpy bitwise.
// 512 blocks, VGPR~88 -> all co-resident; store-before-poll per block.
// ---------------------------------------------------------------------------
__global__ __attribute__((amdgpu_flat_work_group_size(FPS_T, FPS_T),
                          amdgpu_waves_per_eu(2, 2)))
void fps_kernel(const float* __restrict__ xyz, float* __restrict__ qout,
                unsigned long long* __restrict__ gslot) {
  const int gid = blockIdx.x;
  const int xcd = gid & 7;          // round-robin dispatch: block i -> XCD i%8
  const int s = gid >> 3;
  const int b = xcd + 8 * (s >> 3); // all 8 eighths of batch b on same XCD
  const int q = s & 7;
  const int t = threadIdx.x;
  const int w = t >> 6;             // wave id 0..3
  const int lane = t & 63;

  const float* __restrict__ base = xyz + (size_t)b * (FPS_N * 3);
  const float4* __restrict__ base4 =
      (const float4*)(base + (size_t)q * PPB * 3) + (size_t)t * (PPT * 3 / 4);
  float* qb = qout + (size_t)b * (NQ * 3);
  unsigned long long* bslot = gslot + (size_t)b * (NQ * NBLK);

  __shared__ unsigned long long sredp[2][4];   // parity-dbuf wave partials

  // persistent registers: coords 12 float4 = 48 VGPR, dist 4 float4 = 16 VGPR
  float4 C[PPT * 3 / 4];
#pragma unroll
  for (int i = 0; i < PPT * 3 / 4; ++i) C[i] = base4[i];
#pragma unroll
  for (int i = 0; i < PPT * 3 / 4; ++i) {   // pin: forbid remat
    asm volatile("" : "+v"(C[i].x), "+v"(C[i].y), "+v"(C[i].z), "+v"(C[i].w));
  }
  float4 Dst[NCH];
#pragma unroll
  for (int c = 0; c < NCH; ++c) Dst[c] = make_float4(1e10f, 1e10f, 1e10f, 1e10f);

  if (q == 0 && t == 0) { qb[0] = base[0]; qb[1] = base[1]; qb[2] = base[2]; }
  float cx = base[0], cy = base[1], cz = base[2];   // inds[0] == 0

#pragma unroll 1
  for (int j = 1; j < NQ; ++j) {
    float best = -1.0f;
    int bik = 0;

#pragma unroll
    for (int c = 0; c < NCH; ++c) {
      const float4 a4 = C[3 * c + 0];
      const float4 b4 = C[3 * c + 1];
      const float4 c4 = C[3 * c + 2];
      // unpack 12 floats -> 4 points (register renaming, no real ops)
      const float px[4] = {a4.x, a4.w, b4.z, c4.y};
      const float py[4] = {a4.y, b4.x, b4.w, c4.z};
      const float pz[4] = {a4.z, b4.y, c4.x, c4.w};
      const float dold[4] = {Dst[c].x, Dst[c].y, Dst[c].z, Dst[c].w};
      float dnew[4];
#pragma unroll
      for (int i = 0; i < 4; ++i) {
        const float dx = __fsub_rn(px[i], cx);
        const float dy = __fsub_rn(py[i], cy);
        const float dz = __fsub_rn(pz[i], cz);
        // numpy order: (dx^2 + dy^2) + dz^2, no fma
        const float d = __fadd_rn(__fadd_rn(__fmul_rn(dx, dx), __fmul_rn(dy, dy)),
                                  __fmul_rn(dz, dz));
        const float nd = fminf(dold[i], d);
        dnew[i] = nd;
        if (nd > best) { best = nd; bik = c * 4 + i; }  // strict >: first occ.
      }
      Dst[c] = make_float4(dnew[0], dnew[1], dnew[2], dnew[3]);
    }
    const int bi = q * PPB + t * PPT + bik;   // global point index
    // pack: monotone in dist (f32>=0); ~idx -> max picks smallest index
    unsigned long long p =
        ((unsigned long long)(unsigned int)__float_as_int(best) << 32) |
        (unsigned int)~(unsigned int)bi;

    // wave (64-lane) butterfly max on pack
#pragma unroll
    for (int off = 32; off; off >>= 1) {
      const unsigned long long o = __shfl_xor(p, off);
      if (o > p) p = o;
    }
    if (lane == 0) sredp[j & 1][w] = p;
    __syncthreads();   // the only barrier per iteration

    // every wave: block max from the 4 partials (lanes 0-3, 2-step bf)
    unsigned long long bp = 0;
    if (lane < 4) bp = sredp[j & 1][lane];
#pragma unroll
    for (int off = 1; off < 4; off <<= 1) {
      const unsigned long long o = __shfl_xor(bp, off);
      if (o > bp) bp = o;
    }
    // publish block result: one relaxed u64 store (wave0 lane0)
    if (w == 0 && lane == 0) {
      __hip_atomic_store(&bslot[j * NBLK + q], bp, __ATOMIC_RELAXED,
                         __HIP_MEMORY_SCOPE_AGENT);
    }

    // every wave: lanes 0-7 relaxed-poll the 8-slot 64B line
    unsigned long long own = SENT;
    if (lane < NBLK) {
      const unsigned long long* sl = &bslot[j * NBLK + lane];
      do {
        own = __hip_atomic_load(sl, __ATOMIC_RELAXED, __HIP_MEMORY_SCOPE_AGENT);
      } while (own == SENT);
    }
    // butterfly over the 8 block results (lanes 0-7)
#pragma unroll
    for (int off = 1; off < NBLK; off <<= 1) {
      const unsigned long long o = __shfl_xor(own, off);
      if (o > own) own = o;
    }
    // broadcast winner index; uniform-address centroid gather (L2 broadcast)
    const unsigned int lo =
        __builtin_amdgcn_readfirstlane((unsigned int)(own & 0xffffffffull));
    const int gi = (int)~lo;
    const float* cp = base + 3 * (size_t)gi;
    cx = cp[0]; cy = cp[1]; cz = cp[2];

    if (q == 0 && t == 0) {
      qb[3 * j + 0] = cx; qb[3 * j + 1] = cy; qb[3 * j + 2] = cz;
    }
  }
}

// ---------------------------------------------------------------------------
// Kernel 2: fourier positional embedding + 2-layer MLP, fused. (unchanged)
// ---------------------------------------------------------------------------
__global__ __launch_bounds__(256) void embed_mlp_kernel(
    const float* __restrict__ qxyz, const float* __restrict__ pcmin,
    const float* __restrict__ pcmax, const float* __restrict__ G,
    const float* __restrict__ W1, const float* __restrict__ b1,
    const float* __restrict__ W2, const float* __restrict__ b2,
    float* __restrict__ out) {
  const int b = blockIdx.x >> 2;
  const int n0 = (blockIdx.x & 3) * NT;
  const int tid = threadIdx.x;
  const int ty = tid >> 4, tx = tid & 15;

  __shared__ __align__(16) float P[DD][NT + 4];   // pos
  __shared__ __align__(16) float H[DD][NT + 4];   // hidden
  __shared__ __align__(16) float Wl[64][NT + 4];  // W tile (transposed)
  __shared__ float snorm[NT][3];

  if (tid < NT) {
    const int n = n0 + tid;
    const float qx = qxyz[(size_t)b * (NQ * 3) + 3 * n + 0];
    const float qy = qxyz[(size_t)b * (NQ * 3) + 3 * n + 1];
    const float qz = qxyz[(size_t)b * (NQ * 3) + 3 * n + 2];
    snorm[tid][0] = (qx - pcmin[3 * b + 0]) / (pcmax[3 * b + 0] - pcmin[3 * b + 0]);
    snorm[tid][1] = (qy - pcmin[3 * b + 1]) / (pcmax[3 * b + 1] - pcmin[3 * b + 1]);
    snorm[tid][2] = (qz - pcmin[3 * b + 2]) / (pcmax[3 * b + 2] - pcmin[3 * b + 2]);
  }
  __syncthreads();

  {
    const int nn = tid & 63;
    const int fg = tid >> 6;   // 0..3
    const float nx = snorm[nn][0], ny = snorm[nn][1], nz = snorm[nn][2];
#pragma unroll 4
    for (int ff = 0; ff < 32; ++ff) {
      const int f = fg * 32 + ff;
      const float s = nx * G[f] + ny * G[128 + f] + nz * G[256 + f];
      const float proj = 6.28318530717958647692f * s;
      P[f][nn] = sinf(proj);
      P[f + 128][nn] = cosf(proj);
    }
  }

  for (int layer = 0; layer < 2; ++layer) {
    const float* W = layer ? W2 : W1;
    const float* bias = layer ? b2 : b1;
    const float (*src)[NT + 4] = layer ? H : P;

    for (int dt = 0; dt < 4; ++dt) {
      float acc[4][4] = {};
      for (int kt = 0; kt < 4; ++kt) {
        __syncthreads();
        {  // stage W tile transposed: Wl[c][d] = W[dt*64+d][kt*64+c]
          const int r = tid >> 2;
          const int cb = (tid & 3) * 16;
          const float* wrow = W + (size_t)(dt * 64 + r) * DD + kt * 64 + cb;
#pragma unroll
          for (int i = 0; i < 4; ++i) {
            const float4 v = *(const float4*)(wrow + 4 * i);
            Wl[cb + 4 * i + 0][r] = v.x;
            Wl[cb + 4 * i + 1][r] = v.y;
            Wl[cb + 4 * i + 2][r] = v.z;
            Wl[cb + 4 * i + 3][r] = v.w;
          }
        }
        __syncthreads();
#pragma unroll 8
        for (int cc = 0; cc < 64; ++cc) {
          const float4 a = *(const float4*)&Wl[cc][ty * 4];
          const float4 p4 = *(const float4*)&src[kt * 64 + cc][tx * 4];
          acc[0][0] = fmaf(a.x, p4.x, acc[0][0]);
          acc[0][1] = fmaf(a.x, p4.y, acc[0][1]);
          acc[0][2] = fmaf(a.x, p4.z, acc[0][2]);
          acc[0][3] = fmaf(a.x, p4.w, acc[0][3]);
          acc[1][0] = fmaf(a.y, p4.x, acc[1][0]);
          acc[1][1] = fmaf(a.y, p4.y, acc[1][1]);
          acc[1][2] = fmaf(a.y, p4.z, acc[1][2]);
          acc[1][3] = fmaf(a.y, p4.w, acc[1][3]);
          acc[2][0] = fmaf(a.z, p4.x, acc[2][0]);
          acc[2][1] = fmaf(a.z, p4.y, acc[2][1]);
          acc[2][2] = fmaf(a.z, p4.z, acc[2][2]);
          acc[2][3] = fmaf(a.z, p4.w, acc[2][3]);
          acc[3][0] = fmaf(a.w, p4.x, acc[3][0]);
          acc[3][1] = fmaf(a.w, p4.y, acc[3][1]);
          acc[3][2] = fmaf(a.w, p4.z, acc[3][2]);
          acc[3][3] = fmaf(a.w, p4.w, acc[3][3]);
        }
      }
      if (layer == 0) {
#pragma unroll
        for (int i = 0; i < 4; ++i) {
          const float bv = bias[dt * 64 + ty * 4 + i];
          float4 h;
          h.x = fmaxf(acc[i][0] + bv, 0.f);
          h.y = fmaxf(acc[i][1] + bv, 0.f);
          h.z = fmaxf(acc[i][2] + bv, 0.f);
          h.w = fmaxf(acc[i][3] + bv, 0.f);
          *(float4*)&H[dt * 64 + ty * 4 + i][tx * 4] = h;
        }
      } else {
        float* ob = out + (size_t)b * (DD * NQ);
#pragma unroll
        for (int i = 0; i < 4; ++i) {
          const float bv = bias[dt * 64 + ty * 4 + i];
          float4 h;
          h.x = fmaxf(acc[i][0] + bv, 0.f);
          h.y = fmaxf(acc[i][1] + bv, 0.f);
          h.z = fmaxf(acc[i][2] + bv, 0.f);
          h.w = fmaxf(acc[i][3] + bv, 0.f);
          *(float4*)(ob + (size_t)(dt * 64 + ty * 4 + i) * NQ + n0 + tx * 4) = h;
        }
      }
    }
  }
}

extern "C" void kernel_launch(void* const* d_in, const int* in_sizes, int n_in,
                              void* d_out, int out_size, void* d_ws, size_t ws_size,
                              hipStream_t stream) {
  (void)in_sizes; (void)n_in; (void)ws_size; (void)out_size;
  const float* xyz   = (const float*)d_in[0];
  const float* pcmin = (const float*)d_in[1];
  const float* pcmax = (const float*)d_in[2];
  const float* G     = (const float*)d_in[3];
  const float* W1    = (const float*)d_in[4];
  const float* b1    = (const float*)d_in[5];
  const float* W2    = (const float*)d_in[6];
  const float* b2    = (const float*)d_in[7];

  float* qxyz  = (float*)d_out;                       // [64][256][3]
  float* embed = qxyz + (size_t)B_BATCH * NQ * 3;     // [64][256][256]

  unsigned long long* gslot = (unsigned long long*)d_ws;

  // sentinel-fill slots every launch (deterministic across graph replays)
  hipMemsetAsync(d_ws, 0xFF, WS_CLEAR_BYTES, stream);

  hipLaunchKernelGGL(fps_kernel, dim3(B_BATCH * NBLK), dim3(FPS_T), 0, stream,
                     xyz, qxyz, gslot);
  hipLaunchKernelGGL(embed_mlp_kernel, dim3(B_BATCH * 4), dim3(256), 0, stream,
                     qxyz, pcmin, pcmax, G, W1, b1, W2, b2, embed);
}

// Round 16
// 640.281 us; speedup vs baseline: 17.2980x; 1.0579x over previous
//
#include <hip/hip_runtime.h>

#define FPS_N 32768
#define FPS_T 256          // threads per block
#define NBLK 8             // blocks per batch
#define PPB (FPS_N / NBLK) // 4096 points per block
#define PPT (PPB / FPS_T)  // 16 points per thread
#define NCH (PPT / 4)      // 4 four-point chunks per thread
#define NQ 256
#define DD 256
#define NT 64              // n-tile for MLP kernel
#define B_BATCH 64
#define SLOT_STRIDE 8      // u64s per slot: one 64B cache line each

// d_ws: u64 slot[64][256][8][8] = 8 MB, zeroed per launch
#define WS_CLEAR_BYTES (B_BATCH * NQ * NBLK * SLOT_STRIDE * 8)

// ---------------------------------------------------------------------------
// Kernel 1: furthest point sampling, EIGHT blocks (256 thr) per batch.
// EXACT R12 skeleton (505us: two barriers, wave0-only combine, t0 gather —
// R13/R14/R15 proved every deviation regresses) with ONE change:
// each slot is padded to its own 64B cache line (SLOT_STRIDE=8).
// R12-R15 collation: all 8 slots shared one 64B line; L2 serializes
// same-line atomics, so 8 stores + 64 poll lanes per round became a ~1us
// serial queue on one L2 bank. Distinct lines -> bank-parallel polls.
// pack = distbits<<32 | ~idx (monotone f32>=0; ~idx = smallest index on
// ties = jnp.argmax first-occurrence); sentinel 0 (valid pack never 0).
// Polls: few lanes (wave0 lanes 0-7), RELAXED (R13 lesson).
// Arithmetic matches numpy bitwise: sub, mul, add (no FMA), fminf.
// 512 blocks x 88 VGPR -> all co-resident; store-before-poll.
// ---------------------------------------------------------------------------
__global__ __attribute__((amdgpu_flat_work_group_size(FPS_T, FPS_T),
                          amdgpu_waves_per_eu(2, 2)))
void fps_kernel(const float* __restrict__ xyz, float* __restrict__ qout,
                unsigned long long* __restrict__ gslot) {
  const int gid = blockIdx.x;
  const int xcd = gid & 7;          // round-robin dispatch: block i -> XCD i%8
  const int s = gid >> 3;
  const int b = xcd + 8 * (s >> 3); // all 8 eighths of batch b on same XCD
  const int q = s & 7;
  const int t = threadIdx.x;

  const float* __restrict__ base = xyz + (size_t)b * (FPS_N * 3);
  const float4* __restrict__ base4 =
      (const float4*)(base + (size_t)q * PPB * 3) + (size_t)t * (PPT * 3 / 4);
  float* qb = qout + (size_t)b * (NQ * 3);
  unsigned long long* bslot = gslot + (size_t)b * (NQ * NBLK * SLOT_STRIDE);

  __shared__ unsigned long long sred[FPS_T / 64];
  __shared__ float4 bc;   // broadcast: cx, cy, cz

  // persistent registers: coords 12 float4 = 48 VGPR, dist 4 float4 = 16 VGPR
  float4 C[PPT * 3 / 4];
#pragma unroll
  for (int i = 0; i < PPT * 3 / 4; ++i) C[i] = base4[i];
#pragma unroll
  for (int i = 0; i < PPT * 3 / 4; ++i) {   // pin: forbid remat
    asm volatile("" : "+v"(C[i].x), "+v"(C[i].y), "+v"(C[i].z), "+v"(C[i].w));
  }
  float4 Dst[NCH];
#pragma unroll
  for (int c = 0; c < NCH; ++c) Dst[c] = make_float4(1e10f, 1e10f, 1e10f, 1e10f);

  if (q == 0 && t == 0) { qb[0] = base[0]; qb[1] = base[1]; qb[2] = base[2]; }
  float cx = base[0], cy = base[1], cz = base[2];   // inds[0] == 0

#pragma unroll 1
  for (int j = 1; j < NQ; ++j) {
    float best = -1.0f;
    int bik = 0;

#pragma unroll
    for (int c = 0; c < NCH; ++c) {
      const float4 a4 = C[3 * c + 0];
      const float4 b4 = C[3 * c + 1];
      const float4 c4 = C[3 * c + 2];
      // unpack 12 floats -> 4 points (register renaming, no real ops)
      const float px[4] = {a4.x, a4.w, b4.z, c4.y};
      const float py[4] = {a4.y, b4.x, b4.w, c4.z};
      const float pz[4] = {a4.z, b4.y, c4.x, c4.w};
      const float dold[4] = {Dst[c].x, Dst[c].y, Dst[c].z, Dst[c].w};
      float dnew[4];
#pragma unroll
      for (int i = 0; i < 4; ++i) {
        const float dx = __fsub_rn(px[i], cx);
        const float dy = __fsub_rn(py[i], cy);
        const float dz = __fsub_rn(pz[i], cz);
        // numpy order: (dx^2 + dy^2) + dz^2, no fma
        const float d = __fadd_rn(__fadd_rn(__fmul_rn(dx, dx), __fmul_rn(dy, dy)),
                                  __fmul_rn(dz, dz));
        const float nd = fminf(dold[i], d);
        dnew[i] = nd;
        if (nd > best) { best = nd; bik = c * 4 + i; }  // strict >: first occ.
      }
      Dst[c] = make_float4(dnew[0], dnew[1], dnew[2], dnew[3]);
    }
    int bi = q * PPB + t * PPT + bik;   // global point index

    // wave (64-lane) argmax reduce with first-index tie-break
#pragma unroll
    for (int off = 32; off; off >>= 1) {
      const float ov = __shfl_xor(best, off);
      const int oi = __shfl_xor(bi, off);
      if (ov > best || (ov == best && oi < bi)) { best = ov; bi = oi; }
    }
    // pack: monotone in dist (f32>=0), ~idx -> max picks smallest index
    if ((t & 63) == 0) {
      sred[t >> 6] = ((unsigned long long)(unsigned int)__float_as_int(best) << 32) |
                     (unsigned int)~(unsigned int)bi;
    }
    __syncthreads();

    if (t < 64) {   // wave 0 handles block combine + cross-block sync
      unsigned long long p = sred[t & 3];
#pragma unroll
      for (int off = 1; off < 4; off <<= 1) {
        const unsigned long long o = __shfl_xor(p, off);
        if (o > p) p = o;
      }
      // p = this block's pack (identical in lanes 0-7)
      if (t == 0) {
        __hip_atomic_store(&bslot[(j * NBLK + q) * SLOT_STRIDE], p,
                           __ATOMIC_RELAXED, __HIP_MEMORY_SCOPE_AGENT);
      }
      unsigned long long rp = 0;
      if (t < NBLK) {
        const unsigned long long* sl = &bslot[(j * NBLK + t) * SLOT_STRIDE];
        do {
          rp = __hip_atomic_load(sl, __ATOMIC_RELAXED, __HIP_MEMORY_SCOPE_AGENT);
        } while (rp == 0ull);
      }
#pragma unroll
      for (int off = 1; off < NBLK; off <<= 1) {
        const unsigned long long o = __shfl_xor(rp, off);
        if (o > rp) rp = o;
      }
      if (t == 0) {
        const int gi = (int)~(unsigned int)(rp & 0xffffffffull);
        const float* cp = base + 3 * (size_t)gi;
        const float ncx = cp[0], ncy = cp[1], ncz = cp[2];
        bc = make_float4(ncx, ncy, ncz, 0.f);
        if (q == 0) { qb[3 * j + 0] = ncx; qb[3 * j + 1] = ncy; qb[3 * j + 2] = ncz; }
      }
    }
    __syncthreads();
    cx = bc.x; cy = bc.y; cz = bc.z;
  }
}

// ---------------------------------------------------------------------------
// Kernel 2: fourier positional embedding + 2-layer MLP, fused. (unchanged)
// ---------------------------------------------------------------------------
__global__ __launch_bounds__(256) void embed_mlp_kernel(
    const float* __restrict__ qxyz, const float* __restrict__ pcmin,
    const float* __restrict__ pcmax, const float* __restrict__ G,
    const float* __restrict__ W1, const float* __restrict__ b1,
    const float* __restrict__ W2, const float* __restrict__ b2,
    float* __restrict__ out) {
  const int b = blockIdx.x >> 2;
  const int n0 = (blockIdx.x & 3) * NT;
  const int tid = threadIdx.x;
  const int ty = tid >> 4, tx = tid & 15;

  __shared__ __align__(16) float P[DD][NT + 4];   // pos
  __shared__ __align__(16) float H[DD][NT + 4];   // hidden
  __shared__ __align__(16) float Wl[64][NT + 4];  // W tile (transposed)
  __shared__ float snorm[NT][3];

  if (tid < NT) {
    const int n = n0 + tid;
    const float qx = qxyz[(size_t)b * (NQ * 3) + 3 * n + 0];
    const float qy = qxyz[(size_t)b * (NQ * 3) + 3 * n + 1];
    const float qz = qxyz[(size_t)b * (NQ * 3) + 3 * n + 2];
    snorm[tid][0] = (qx - pcmin[3 * b + 0]) / (pcmax[3 * b + 0] - pcmin[3 * b + 0]);
    snorm[tid][1] = (qy - pcmin[3 * b + 1]) / (pcmax[3 * b + 1] - pcmin[3 * b + 1]);
    snorm[tid][2] = (qz - pcmin[3 * b + 2]) / (pcmax[3 * b + 2] - pcmin[3 * b + 2]);
  }
  __syncthreads();

  {
    const int nn = tid & 63;
    const int fg = tid >> 6;   // 0..3
    const float nx = snorm[nn][0], ny = snorm[nn][1], nz = snorm[nn][2];
#pragma unroll 4
    for (int ff = 0; ff < 32; ++ff) {
      const int f = fg * 32 + ff;
      const float s = nx * G[f] + ny * G[128 + f] + nz * G[256 + f];
      const float proj = 6.28318530717958647692f * s;
      P[f][nn] = sinf(proj);
      P[f + 128][nn] = cosf(proj);
    }
  }

  for (int layer = 0; layer < 2; ++layer) {
    const float* W = layer ? W2 : W1;
    const float* bias = layer ? b2 : b1;
    const float (*src)[NT + 4] = layer ? H : P;

    for (int dt = 0; dt < 4; ++dt) {
      float acc[4][4] = {};
      for (int kt = 0; kt < 4; ++kt) {
        __syncthreads();
        {  // stage W tile transposed: Wl[c][d] = W[dt*64+d][kt*64+c]
          const int r = tid >> 2;
          const int cb = (tid & 3) * 16;
          const float* wrow = W + (size_t)(dt * 64 + r) * DD + kt * 64 + cb;
#pragma unroll
          for (int i = 0; i < 4; ++i) {
            const float4 v = *(const float4*)(wrow + 4 * i);
            Wl[cb + 4 * i + 0][r] = v.x;
            Wl[cb + 4 * i + 1][r] = v.y;
            Wl[cb + 4 * i + 2][r] = v.z;
            Wl[cb + 4 * i + 3][r] = v.w;
          }
        }
        __syncthreads();
#pragma unroll 8
        for (int cc = 0; cc < 64; ++cc) {
          const float4 a = *(const float4*)&Wl[cc][ty * 4];
          const float4 p4 = *(const float4*)&src[kt * 64 + cc][tx * 4];
          acc[0][0] = fmaf(a.x, p4.x, acc[0][0]);
          acc[0][1] = fmaf(a.x, p4.y, acc[0][1]);
          acc[0][2] = fmaf(a.x, p4.z, acc[0][2]);
          acc[0][3] = fmaf(a.x, p4.w, acc[0][3]);
          acc[1][0] = fmaf(a.y, p4.x, acc[1][0]);
          acc[1][1] = fmaf(a.y, p4.y, acc[1][1]);
          acc[1][2] = fmaf(a.y, p4.z, acc[1][2]);
          acc[1][3] = fmaf(a.y, p4.w, acc[1][3]);
          acc[2][0] = fmaf(a.z, p4.x, acc[2][0]);
          acc[2][1] = fmaf(a.z, p4.y, acc[2][1]);
          acc[2][2] = fmaf(a.z, p4.z, acc[2][2]);
          acc[2][3] = fmaf(a.z, p4.w, acc[2][3]);
          acc[3][0] = fmaf(a.w, p4.x, acc[3][0]);
          acc[3][1] = fmaf(a.w, p4.y, acc[3][1]);
          acc[3][2] = fmaf(a.w, p4.z, acc[3][2]);
          acc[3][3] = fmaf(a.w, p4.w, acc[3][3]);
        }
      }
      if (layer == 0) {
#pragma unroll
        for (int i = 0; i < 4; ++i) {
          const float bv = bias[dt * 64 + ty * 4 + i];
          float4 h;
          h.x = fmaxf(acc[i][0] + bv, 0.f);
          h.y = fmaxf(acc[i][1] + bv, 0.f);
          h.z = fmaxf(acc[i][2] + bv, 0.f);
          h.w = fmaxf(acc[i][3] + bv, 0.f);
          *(float4*)&H[dt * 64 + ty * 4 + i][tx * 4] = h;
        }
      } else {
        float* ob = out + (size_t)b * (DD * NQ);
#pragma unroll
        for (int i = 0; i < 4; ++i) {
          const float bv = bias[dt * 64 + ty * 4 + i];
          float4 h;
          h.x = fmaxf(acc[i][0] + bv, 0.f);
          h.y = fmaxf(acc[i][1] + bv, 0.f);
          h.z = fmaxf(acc[i][2] + bv, 0.f);
          h.w = fmaxf(acc[i][3] + bv, 0.f);
          *(float4*)(ob + (size_t)(dt * 64 + ty * 4 + i) * NQ + n0 + tx * 4) = h;
        }
      }
    }
  }
}

extern "C" void kernel_launch(void* const* d_in, const int* in_sizes, int n_in,
                              void* d_out, int out_size, void* d_ws, size_t ws_size,
                              hipStream_t stream) {
  (void)in_sizes; (void)n_in; (void)ws_size; (void)out_size;
  const float* xyz   = (const float*)d_in[0];
  const float* pcmin = (const float*)d_in[1];
  const float* pcmax = (const float*)d_in[2];
  const float* G     = (const float*)d_in[3];
  const float* W1    = (const float*)d_in[4];
  const float* b1    = (const float*)d_in[5];
  const float* W2    = (const float*)d_in[6];
  const float* b2    = (const float*)d_in[7];

  float* qxyz  = (float*)d_out;                       // [64][256][3]
  float* embed = qxyz + (size_t)B_BATCH * NQ * 3;     // [64][256][256]

  unsigned long long* gslot = (unsigned long long*)d_ws;

  // clear slots every launch (deterministic across graph replays)
  hipMemsetAsync(d_ws, 0, WS_CLEAR_BYTES, stream);

  hipLaunchKernelGGL(fps_kernel, dim3(B_BATCH * NBLK), dim3(FPS_T), 0, stream,
                     xyz, qxyz, gslot);
  hipLaunchKernelGGL(embed_mlp_kernel, dim3(B_BATCH * 4), dim3(256), 0, stream,
                     qxyz, pcmin, pcmax, G, W1, b1, W2, b2, embed);
}

// Round 17
// 607.404 us; speedup vs baseline: 18.2343x; 1.0541x over previous
//
#include <hip/hip_runtime.h>

#define FPS_N 32768
#define FPS_T 512          // threads per block: 8 waves, 1 block/CU
#define NBLK 4             // blocks per batch
#define PPB (FPS_N / NBLK) // 8192 points per block
#define PPT (PPB / FPS_T)  // 16 points per thread
#define NCH (PPT / 4)      // 4 four-point chunks per thread
#define NQ 256
#define DD 256
#define NT 64              // n-tile for MLP kernel
#define B_BATCH 64
#define RND_STRIDE 8       // u64s per round: 4 slots used, 64B-line aligned

// d_ws: u64 slot[64][256][8] = 1 MB, zeroed per launch
#define WS_CLEAR_BYTES (B_BATCH * NQ * RND_STRIDE * 8)

// ---------------------------------------------------------------------------
// Kernel 1: furthest point sampling, FOUR blocks (512 thr) per batch.
// Topology change from R12 (the 505us best): NBLK 8->4 and 1 block/CU.
//  - 256 blocks on 256 CUs: no CU sharing -> no cross-batch scheduling
//    jitter inside the 255x serial sync chain.
//  - skew term is max over 4 blocks, not 8; 4 stores/round, not 8.
//  - all 4 slots of a round live in ONE 64B line (R16 refuted per-slot
//    padding: same-line polls coalesce+broadcast, multi-line polls cost
//    +55us). Rounds are padded apart (RND_STRIDE=8) so round j+1 stores
//    never touch the line being polled for round j.
// VGPR: cap at 512 thr = 128 (R7); demand = coords 12xfloat4 (48) +
// dist 4xfloat4 (16) + misc ~25 = ~90 -> resident, no spill.
// Combine (R12 structure, proven): wave bf -> 8 LDS partials -> barrier ->
// wave0 reads sred[t&7], 3-step bf -> t0 one relaxed u64 store ->
// lanes 0-3 relaxed-poll one line -> 2-step bf -> t0 uniform centroid
// gather -> LDS bc -> barrier. Polls few-lane + RELAXED (R13 lesson).
// pack = distbits<<32 | ~idx (monotone f32>=0; ~idx = smallest index on
// ties = jnp.argmax first-occurrence). Arithmetic matches numpy bitwise.
// ---------------------------------------------------------------------------
__global__ __attribute__((amdgpu_flat_work_group_size(FPS_T, FPS_T),
                          amdgpu_waves_per_eu(2, 2)))
void fps_kernel(const float* __restrict__ xyz, float* __restrict__ qout,
                unsigned long long* __restrict__ gslot) {
  const int gid = blockIdx.x;
  const int xcd = gid & 7;          // round-robin dispatch: block i -> XCD i%8
  const int s = gid >> 3;
  const int b = xcd + 8 * (s >> 2); // all 4 quarters of batch b on same XCD
  const int q = s & 3;
  const int t = threadIdx.x;

  const float* __restrict__ base = xyz + (size_t)b * (FPS_N * 3);
  const float4* __restrict__ base4 =
      (const float4*)(base + (size_t)q * PPB * 3) + (size_t)t * (PPT * 3 / 4);
  float* qb = qout + (size_t)b * (NQ * 3);
  unsigned long long* bslot = gslot + (size_t)b * (NQ * RND_STRIDE);

  __shared__ unsigned long long sred[FPS_T / 64];   // 8 wave partials
  __shared__ float4 bc;   // broadcast: cx, cy, cz

  // persistent registers: coords 12 float4 = 48 VGPR, dist 4 float4 = 16 VGPR
  float4 C[PPT * 3 / 4];
#pragma unroll
  for (int i = 0; i < PPT * 3 / 4; ++i) C[i] = base4[i];
#pragma unroll
  for (int i = 0; i < PPT * 3 / 4; ++i) {   // pin: forbid remat
    asm volatile("" : "+v"(C[i].x), "+v"(C[i].y), "+v"(C[i].z), "+v"(C[i].w));
  }
  float4 Dst[NCH];
#pragma unroll
  for (int c = 0; c < NCH; ++c) Dst[c] = make_float4(1e10f, 1e10f, 1e10f, 1e10f);

  if (q == 0 && t == 0) { qb[0] = base[0]; qb[1] = base[1]; qb[2] = base[2]; }
  float cx = base[0], cy = base[1], cz = base[2];   // inds[0] == 0

#pragma unroll 1
  for (int j = 1; j < NQ; ++j) {
    float best = -1.0f;
    int bik = 0;

#pragma unroll
    for (int c = 0; c < NCH; ++c) {
      const float4 a4 = C[3 * c + 0];
      const float4 b4 = C[3 * c + 1];
      const float4 c4 = C[3 * c + 2];
      // unpack 12 floats -> 4 points (register renaming, no real ops)
      const float px[4] = {a4.x, a4.w, b4.z, c4.y};
      const float py[4] = {a4.y, b4.x, b4.w, c4.z};
      const float pz[4] = {a4.z, b4.y, c4.x, c4.w};
      const float dold[4] = {Dst[c].x, Dst[c].y, Dst[c].z, Dst[c].w};
      float dnew[4];
#pragma unroll
      for (int i = 0; i < 4; ++i) {
        const float dx = __fsub_rn(px[i], cx);
        const float dy = __fsub_rn(py[i], cy);
        const float dz = __fsub_rn(pz[i], cz);
        // numpy order: (dx^2 + dy^2) + dz^2, no fma
        const float d = __fadd_rn(__fadd_rn(__fmul_rn(dx, dx), __fmul_rn(dy, dy)),
                                  __fmul_rn(dz, dz));
        const float nd = fminf(dold[i], d);
        dnew[i] = nd;
        if (nd > best) { best = nd; bik = c * 4 + i; }  // strict >: first occ.
      }
      Dst[c] = make_float4(dnew[0], dnew[1], dnew[2], dnew[3]);
    }
    int bi = q * PPB + t * PPT + bik;   // global point index

    // wave (64-lane) argmax reduce with first-index tie-break
#pragma unroll
    for (int off = 32; off; off >>= 1) {
      const float ov = __shfl_xor(best, off);
      const int oi = __shfl_xor(bi, off);
      if (ov > best || (ov == best && oi < bi)) { best = ov; bi = oi; }
    }
    // pack: monotone in dist (f32>=0), ~idx -> max picks smallest index
    if ((t & 63) == 0) {
      sred[t >> 6] = ((unsigned long long)(unsigned int)__float_as_int(best) << 32) |
                     (unsigned int)~(unsigned int)bi;
    }
    __syncthreads();

    if (t < 64) {   // wave 0 handles block combine + cross-block sync
      unsigned long long p = sred[t & 7];
#pragma unroll
      for (int off = 1; off < 8; off <<= 1) {
        const unsigned long long o = __shfl_xor(p, off);
        if (o > p) p = o;
      }
      // p = this block's pack (identical in all 64 lanes)
      if (t == 0) {
        __hip_atomic_store(&bslot[j * RND_STRIDE + q], p, __ATOMIC_RELAXED,
                           __HIP_MEMORY_SCOPE_AGENT);
      }
      unsigned long long rp = 0;
      if (t < NBLK) {
        const unsigned long long* sl = &bslot[j * RND_STRIDE + t];
        do {
          rp = __hip_atomic_load(sl, __ATOMIC_RELAXED, __HIP_MEMORY_SCOPE_AGENT);
        } while (rp == 0ull);
      }
#pragma unroll
      for (int off = 1; off < NBLK; off <<= 1) {
        const unsigned long long o = __shfl_xor(rp, off);
        if (o > rp) rp = o;
      }
      if (t == 0) {
        const int gi = (int)~(unsigned int)(rp & 0xffffffffull);
        const float* cp = base + 3 * (size_t)gi;
        const float ncx = cp[0], ncy = cp[1], ncz = cp[2];
        bc = make_float4(ncx, ncy, ncz, 0.f);
        if (q == 0) { qb[3 * j + 0] = ncx; qb[3 * j + 1] = ncy; qb[3 * j + 2] = ncz; }
      }
    }
    __syncthreads();
    cx = bc.x; cy = bc.y; cz = bc.z;
  }
}

// ---------------------------------------------------------------------------
// Kernel 2: fourier positional embedding + 2-layer MLP, fused. (unchanged)
// ---------------------------------------------------------------------------
__global__ __launch_bounds__(256) void embed_mlp_kernel(
    const float* __restrict__ qxyz, const float* __restrict__ pcmin,
    const float* __restrict__ pcmax, const float* __restrict__ G,
    const float* __restrict__ W1, const float* __restrict__ b1,
    const float* __restrict__ W2, const float* __restrict__ b2,
    float* __restrict__ out) {
  const int b = blockIdx.x >> 2;
  const int n0 = (blockIdx.x & 3) * NT;
  const int tid = threadIdx.x;
  const int ty = tid >> 4, tx = tid & 15;

  __shared__ __align__(16) float P[DD][NT + 4];   // pos
  __shared__ __align__(16) float H[DD][NT + 4];   // hidden
  __shared__ __align__(16) float Wl[64][NT + 4];  // W tile (transposed)
  __shared__ float snorm[NT][3];

  if (tid < NT) {
    const int n = n0 + tid;
    const float qx = qxyz[(size_t)b * (NQ * 3) + 3 * n + 0];
    const float qy = qxyz[(size_t)b * (NQ * 3) + 3 * n + 1];
    const float qz = qxyz[(size_t)b * (NQ * 3) + 3 * n + 2];
    snorm[tid][0] = (qx - pcmin[3 * b + 0]) / (pcmax[3 * b + 0] - pcmin[3 * b + 0]);
    snorm[tid][1] = (qy - pcmin[3 * b + 1]) / (pcmax[3 * b + 1] - pcmin[3 * b + 1]);
    snorm[tid][2] = (qz - pcmin[3 * b + 2]) / (pcmax[3 * b + 2] - pcmin[3 * b + 2]);
  }
  __syncthreads();

  {
    const int nn = tid & 63;
    const int fg = tid >> 6;   // 0..3
    const float nx = snorm[nn][0], ny = snorm[nn][1], nz = snorm[nn][2];
#pragma unroll 4
    for (int ff = 0; ff < 32; ++ff) {
      const int f = fg * 32 + ff;
      const float s = nx * G[f] + ny * G[128 + f] + nz * G[256 + f];
      const float proj = 6.28318530717958647692f * s;
      P[f][nn] = sinf(proj);
      P[f + 128][nn] = cosf(proj);
    }
  }

  for (int layer = 0; layer < 2; ++layer) {
    const float* W = layer ? W2 : W1;
    const float* bias = layer ? b2 : b1;
    const float (*src)[NT + 4] = layer ? H : P;

    for (int dt = 0; dt < 4; ++dt) {
      float acc[4][4] = {};
      for (int kt = 0; kt < 4; ++kt) {
        __syncthreads();
        {  // stage W tile transposed: Wl[c][d] = W[dt*64+d][kt*64+c]
          const int r = tid >> 2;
          const int cb = (tid & 3) * 16;
          const float* wrow = W + (size_t)(dt * 64 + r) * DD + kt * 64 + cb;
#pragma unroll
          for (int i = 0; i < 4; ++i) {
            const float4 v = *(const float4*)(wrow + 4 * i);
            Wl[cb + 4 * i + 0][r] = v.x;
            Wl[cb + 4 * i + 1][r] = v.y;
            Wl[cb + 4 * i + 2][r] = v.z;
            Wl[cb + 4 * i + 3][r] = v.w;
          }
        }
        __syncthreads();
#pragma unroll 8
        for (int cc = 0; cc < 64; ++cc) {
          const float4 a = *(const float4*)&Wl[cc][ty * 4];
          const float4 p4 = *(const float4*)&src[kt * 64 + cc][tx * 4];
          acc[0][0] = fmaf(a.x, p4.x, acc[0][0]);
          acc[0][1] = fmaf(a.x, p4.y, acc[0][1]);
          acc[0][2] = fmaf(a.x, p4.z, acc[0][2]);
          acc[0][3] = fmaf(a.x, p4.w, acc[0][3]);
          acc[1][0] = fmaf(a.y, p4.x, acc[1][0]);
          acc[1][1] = fmaf(a.y, p4.y, acc[1][1]);
          acc[1][2] = fmaf(a.y, p4.z, acc[1][2]);
          acc[1][3] = fmaf(a.y, p4.w, acc[1][3]);
          acc[2][0] = fmaf(a.z, p4.x, acc[2][0]);
          acc[2][1] = fmaf(a.z, p4.y, acc[2][1]);
          acc[2][2] = fmaf(a.z, p4.z, acc[2][2]);
          acc[2][3] = fmaf(a.z, p4.w, acc[2][3]);
          acc[3][0] = fmaf(a.w, p4.x, acc[3][0]);
          acc[3][1] = fmaf(a.w, p4.y, acc[3][1]);
          acc[3][2] = fmaf(a.w, p4.z, acc[3][2]);
          acc[3][3] = fmaf(a.w, p4.w, acc[3][3]);
        }
      }
      if (layer == 0) {
#pragma unroll
        for (int i = 0; i < 4; ++i) {
          const float bv = bias[dt * 64 + ty * 4 + i];
          float4 h;
          h.x = fmaxf(acc[i][0] + bv, 0.f);
          h.y = fmaxf(acc[i][1] + bv, 0.f);
          h.z = fmaxf(acc[i][2] + bv, 0.f);
          h.w = fmaxf(acc[i][3] + bv, 0.f);
          *(float4*)&H[dt * 64 + ty * 4 + i][tx * 4] = h;
        }
      } else {
        float* ob = out + (size_t)b * (DD * NQ);
#pragma unroll
        for (int i = 0; i < 4; ++i) {
          const float bv = bias[dt * 64 + ty * 4 + i];
          float4 h;
          h.x = fmaxf(acc[i][0] + bv, 0.f);
          h.y = fmaxf(acc[i][1] + bv, 0.f);
          h.z = fmaxf(acc[i][2] + bv, 0.f);
          h.w = fmaxf(acc[i][3] + bv, 0.f);
          *(float4*)(ob + (size_t)(dt * 64 + ty * 4 + i) * NQ + n0 + tx * 4) = h;
        }
      }
    }
  }
}

extern "C" void kernel_launch(void* const* d_in, const int* in_sizes, int n_in,
                              void* d_out, int out_size, void* d_ws, size_t ws_size,
                              hipStream_t stream) {
  (void)in_sizes; (void)n_in; (void)ws_size; (void)out_size;
  const float* xyz   = (const float*)d_in[0];
  const float* pcmin = (const float*)d_in[1];
  const float* pcmax = (const float*)d_in[2];
  const float* G     = (const float*)d_in[3];
  const float* W1    = (const float*)d_in[4];
  const float* b1    = (const float*)d_in[5];
  const float* W2    = (const float*)d_in[6];
  const float* b2    = (const float*)d_in[7];

  float* qxyz  = (float*)d_out;                       // [64][256][3]
  float* embed = qxyz + (size_t)B_BATCH * NQ * 3;     // [64][256][256]

  unsigned long long* gslot = (unsigned long long*)d_ws;

  // clear slots every launch (deterministic across graph replays)
  hipMemsetAsync(d_ws, 0, WS_CLEAR_BYTES, stream);

  hipLaunchKernelGGL(fps_kernel, dim3(B_BATCH * NBLK), dim3(FPS_T), 0, stream,
                     xyz, qxyz, gslot);
  hipLaunchKernelGGL(embed_mlp_kernel, dim3(B_BATCH * 4), dim3(256), 0, stream,
                     qxyz, pcmin, pcmax, G, W1, b1, W2, b2, embed);
}

// Round 18
// 586.276 us; speedup vs baseline: 18.8914x; 1.0360x over previous
//
#include <hip/hip_runtime.h>

#define FPS_N 32768
#define FPS_T 256          // threads per block
#define NBLK 8             // blocks per batch
#define PPB (FPS_N / NBLK) // 4096 points per block
#define PPT (PPB / FPS_T)  // 16 points per thread
#define NCH (PPT / 4)      // 4 four-point chunks per thread
#define NQ 256
#define DD 256
#define NT 64              // n-tile for MLP kernel
#define B_BATCH 64

// d_ws: u64 slot[64][256][8] = 1 MB, zeroed per launch
#define WS_CLEAR_BYTES (B_BATCH * NQ * NBLK * 8)

// ---------------------------------------------------------------------------
// Kernel 1: furthest point sampling — EXACT R12 configuration (the empirical
// optimum: 505us fps). R13-R17 attacked the ~1.7us/iter sync chain five ways
// (all-wave acquire poll, coords-ride, 1-barrier, per-slot 64B padding,
// NBLK=4/512thr topology) — every variant regressed or was null. Cause: the
// cross-block slots are serviced at the L3/IF coherence point (per-XCD L2s
// not cross-coherent), so each of the 255 serial rounds pays L3-RT-scale
// store-visibility + poll-detection + skew. This structure is the floor.
// Config: 8 blocks/batch, 256 thr, PPT=16 register-resident (coords 48 +
// dist 16 VGPR, waves_per_eu(2,2) -> no spill, VGPR=88), contiguous slots
// (one 64B line per round: same-line polls coalesce+broadcast — R16),
// few-lane RELAXED polls (R13), pack = distbits<<32 | ~idx (monotone for
// f32>=0; ~idx = smallest-index tie-break = jnp.argmax first-occurrence).
// Arithmetic matches numpy bitwise: sub, mul, add (no FMA), fminf.
// ---------------------------------------------------------------------------
__global__ __attribute__((amdgpu_flat_work_group_size(FPS_T, FPS_T),
                          amdgpu_waves_per_eu(2, 2)))
void fps_kernel(const float* __restrict__ xyz, float* __restrict__ qout,
                unsigned long long* __restrict__ gslot) {
  const int gid = blockIdx.x;
  const int xcd = gid & 7;          // round-robin dispatch: block i -> XCD i%8
  const int s = gid >> 3;
  const int b = xcd + 8 * (s >> 3); // all 8 eighths of batch b on same XCD
  const int q = s & 7;
  const int t = threadIdx.x;

  const float* __restrict__ base = xyz + (size_t)b * (FPS_N * 3);
  const float4* __restrict__ base4 =
      (const float4*)(base + (size_t)q * PPB * 3) + (size_t)t * (PPT * 3 / 4);
  float* qb = qout + (size_t)b * (NQ * 3);
  unsigned long long* bslot = gslot + (size_t)b * (NQ * NBLK);

  __shared__ unsigned long long sred[FPS_T / 64];
  __shared__ float4 bc;   // broadcast: cx, cy, cz

  // persistent registers: coords 12 float4 = 48 VGPR, dist 4 float4 = 16 VGPR
  float4 C[PPT * 3 / 4];
#pragma unroll
  for (int i = 0; i < PPT * 3 / 4; ++i) C[i] = base4[i];
#pragma unroll
  for (int i = 0; i < PPT * 3 / 4; ++i) {   // pin: forbid remat
    asm volatile("" : "+v"(C[i].x), "+v"(C[i].y), "+v"(C[i].z), "+v"(C[i].w));
  }
  float4 Dst[NCH];
#pragma unroll
  for (int c = 0; c < NCH; ++c) Dst[c] = make_float4(1e10f, 1e10f, 1e10f, 1e10f);

  if (q == 0 && t == 0) { qb[0] = base[0]; qb[1] = base[1]; qb[2] = base[2]; }
  float cx = base[0], cy = base[1], cz = base[2];   // inds[0] == 0

#pragma unroll 1
  for (int j = 1; j < NQ; ++j) {
    float best = -1.0f;
    int bik = 0;

#pragma unroll
    for (int c = 0; c < NCH; ++c) {
      const float4 a4 = C[3 * c + 0];
      const float4 b4 = C[3 * c + 1];
      const float4 c4 = C[3 * c + 2];
      // unpack 12 floats -> 4 points (register renaming, no real ops)
      const float px[4] = {a4.x, a4.w, b4.z, c4.y};
      const float py[4] = {a4.y, b4.x, b4.w, c4.z};
      const float pz[4] = {a4.z, b4.y, c4.x, c4.w};
      const float dold[4] = {Dst[c].x, Dst[c].y, Dst[c].z, Dst[c].w};
      float dnew[4];
#pragma unroll
      for (int i = 0; i < 4; ++i) {
        const float dx = __fsub_rn(px[i], cx);
        const float dy = __fsub_rn(py[i], cy);
        const float dz = __fsub_rn(pz[i], cz);
        // numpy order: (dx^2 + dy^2) + dz^2, no fma
        const float d = __fadd_rn(__fadd_rn(__fmul_rn(dx, dx), __fmul_rn(dy, dy)),
                                  __fmul_rn(dz, dz));
        const float nd = fminf(dold[i], d);
        dnew[i] = nd;
        if (nd > best) { best = nd; bik = c * 4 + i; }  // strict >: first occ.
      }
      Dst[c] = make_float4(dnew[0], dnew[1], dnew[2], dnew[3]);
    }
    int bi = q * PPB + t * PPT + bik;   // global point index

    // wave (64-lane) argmax reduce with first-index tie-break
#pragma unroll
    for (int off = 32; off; off >>= 1) {
      const float ov = __shfl_xor(best, off);
      const int oi = __shfl_xor(bi, off);
      if (ov > best || (ov == best && oi < bi)) { best = ov; bi = oi; }
    }
    // pack: monotone in dist (f32>=0), ~idx -> max picks smallest index
    if ((t & 63) == 0) {
      sred[t >> 6] = ((unsigned long long)(unsigned int)__float_as_int(best) << 32) |
                     (unsigned int)~(unsigned int)bi;
    }
    __syncthreads();

    if (t < 64) {   // wave 0 handles block combine + cross-block sync
      unsigned long long p = sred[t & 3];
#pragma unroll
      for (int off = 1; off < 4; off <<= 1) {
        const unsigned long long o = __shfl_xor(p, off);
        if (o > p) p = o;
      }
      // p = this block's pack (identical in lanes 0-7)
      if (t == 0) {
        __hip_atomic_store(&bslot[j * NBLK + q], p, __ATOMIC_RELAXED,
                           __HIP_MEMORY_SCOPE_AGENT);
      }
      unsigned long long rp = 0;
      if (t < NBLK) {
        const unsigned long long* sl = &bslot[j * NBLK + t];
        do {
          rp = __hip_atomic_load(sl, __ATOMIC_RELAXED, __HIP_MEMORY_SCOPE_AGENT);
        } while (rp == 0ull);
      }
#pragma unroll
      for (int off = 1; off < NBLK; off <<= 1) {
        const unsigned long long o = __shfl_xor(rp, off);
        if (o > rp) rp = o;
      }
      if (t == 0) {
        const int gi = (int)~(unsigned int)(rp & 0xffffffffull);
        const float* cp = base + 3 * (size_t)gi;
        const float ncx = cp[0], ncy = cp[1], ncz = cp[2];
        bc = make_float4(ncx, ncy, ncz, 0.f);
        if (q == 0) { qb[3 * j + 0] = ncx; qb[3 * j + 1] = ncy; qb[3 * j + 2] = ncz; }
      }
    }
    __syncthreads();
    cx = bc.x; cy = bc.y; cz = bc.z;
  }
}

// ---------------------------------------------------------------------------
// Kernel 2: fourier positional embedding + 2-layer MLP, fused.
// R17 change: 512 threads/block (was 256) -> 2 waves/SIMD for latency hiding
// (at 1 wave/SIMD the FMA+LDS loop ran ~2.5x above the 27us f32 bound).
// Micro-tile remapped 4dx4n -> 2dx4n (ty 0..31, float2 Wl reads); staging
// split 8 floats/thread. Same proven P/H/Wl layouts (pitch 68). LDS 157KB.
// ---------------------------------------------------------------------------
__global__ __launch_bounds__(512) void embed_mlp_kernel(
    const float* __restrict__ qxyz, const float* __restrict__ pcmin,
    const float* __restrict__ pcmax, const float* __restrict__ G,
    const float* __restrict__ W1, const float* __restrict__ b1,
    const float* __restrict__ W2, const float* __restrict__ b2,
    float* __restrict__ out) {
  const int b = blockIdx.x >> 2;
  const int n0 = (blockIdx.x & 3) * NT;
  const int tid = threadIdx.x;
  const int ty = tid >> 4, tx = tid & 15;   // ty 0..31 (2 d rows), tx*4 = n

  __shared__ __align__(16) float P[DD][NT + 4];   // pos
  __shared__ __align__(16) float H[DD][NT + 4];   // hidden
  __shared__ __align__(16) float Wl[64][NT + 4];  // W tile (transposed)
  __shared__ float snorm[NT][3];

  if (tid < NT) {
    const int n = n0 + tid;
    const float qx = qxyz[(size_t)b * (NQ * 3) + 3 * n + 0];
    const float qy = qxyz[(size_t)b * (NQ * 3) + 3 * n + 1];
    const float qz = qxyz[(size_t)b * (NQ * 3) + 3 * n + 2];
    snorm[tid][0] = (qx - pcmin[3 * b + 0]) / (pcmax[3 * b + 0] - pcmin[3 * b + 0]);
    snorm[tid][1] = (qy - pcmin[3 * b + 1]) / (pcmax[3 * b + 1] - pcmin[3 * b + 1]);
    snorm[tid][2] = (qz - pcmin[3 * b + 2]) / (pcmax[3 * b + 2] - pcmin[3 * b + 2]);
  }
  __syncthreads();

  {
    const int nn = tid & 63;
    const int fg = tid >> 6;   // 0..7
    const float nx = snorm[nn][0], ny = snorm[nn][1], nz = snorm[nn][2];
#pragma unroll 4
    for (int ff = 0; ff < 16; ++ff) {
      const int f = fg * 16 + ff;
      const float s = nx * G[f] + ny * G[128 + f] + nz * G[256 + f];
      const float proj = 6.28318530717958647692f * s;
      P[f][nn] = sinf(proj);
      P[f + 128][nn] = cosf(proj);
    }
  }

  for (int layer = 0; layer < 2; ++layer) {
    const float* W = layer ? W2 : W1;
    const float* bias = layer ? b2 : b1;
    const float (*src)[NT + 4] = layer ? H : P;

    for (int dt = 0; dt < 4; ++dt) {
      float acc[2][4] = {};
      for (int kt = 0; kt < 4; ++kt) {
        __syncthreads();
        {  // stage W tile transposed: Wl[c][d] = W[dt*64+d][kt*64+c]
          const int r = tid >> 3;          // 0..63 : d within tile
          const int cb = (tid & 7) * 8;    // c base within tile
          const float* wrow = W + (size_t)(dt * 64 + r) * DD + kt * 64 + cb;
          const float4 v0 = *(const float4*)(wrow);
          const float4 v1 = *(const float4*)(wrow + 4);
          Wl[cb + 0][r] = v0.x;
          Wl[cb + 1][r] = v0.y;
          Wl[cb + 2][r] = v0.z;
          Wl[cb + 3][r] = v0.w;
          Wl[cb + 4][r] = v1.x;
          Wl[cb + 5][r] = v1.y;
          Wl[cb + 6][r] = v1.z;
          Wl[cb + 7][r] = v1.w;
        }
        __syncthreads();
#pragma unroll 8
        for (int cc = 0; cc < 64; ++cc) {
          const float2 a = *(const float2*)&Wl[cc][ty * 2];
          const float4 p4 = *(const float4*)&src[kt * 64 + cc][tx * 4];
          acc[0][0] = fmaf(a.x, p4.x, acc[0][0]);
          acc[0][1] = fmaf(a.x, p4.y, acc[0][1]);
          acc[0][2] = fmaf(a.x, p4.z, acc[0][2]);
          acc[0][3] = fmaf(a.x, p4.w, acc[0][3]);
          acc[1][0] = fmaf(a.y, p4.x, acc[1][0]);
          acc[1][1] = fmaf(a.y, p4.y, acc[1][1]);
          acc[1][2] = fmaf(a.y, p4.z, acc[1][2]);
          acc[1][3] = fmaf(a.y, p4.w, acc[1][3]);
        }
      }
      if (layer == 0) {
#pragma unroll
        for (int i = 0; i < 2; ++i) {
          const float bv = bias[dt * 64 + ty * 2 + i];
          float4 h;
          h.x = fmaxf(acc[i][0] + bv, 0.f);
          h.y = fmaxf(acc[i][1] + bv, 0.f);
          h.z = fmaxf(acc[i][2] + bv, 0.f);
          h.w = fmaxf(acc[i][3] + bv, 0.f);
          *(float4*)&H[dt * 64 + ty * 2 + i][tx * 4] = h;
        }
      } else {
        float* ob = out + (size_t)b * (DD * NQ);
#pragma unroll
        for (int i = 0; i < 2; ++i) {
          const float bv = bias[dt * 64 + ty * 2 + i];
          float4 h;
          h.x = fmaxf(acc[i][0] + bv, 0.f);
          h.y = fmaxf(acc[i][1] + bv, 0.f);
          h.z = fmaxf(acc[i][2] + bv, 0.f);
          h.w = fmaxf(acc[i][3] + bv, 0.f);
          *(float4*)(ob + (size_t)(dt * 64 + ty * 2 + i) * NQ + n0 + tx * 4) = h;
        }
      }
    }
  }
}

extern "C" void kernel_launch(void* const* d_in, const int* in_sizes, int n_in,
                              void* d_out, int out_size, void* d_ws, size_t ws_size,
                              hipStream_t stream) {
  (void)in_sizes; (void)n_in; (void)ws_size; (void)out_size;
  const float* xyz   = (const float*)d_in[0];
  const float* pcmin = (const float*)d_in[1];
  const float* pcmax = (const float*)d_in[2];
  const float* G     = (const float*)d_in[3];
  const float* W1    = (const float*)d_in[4];
  const float* b1    = (const float*)d_in[5];
  const float* W2    = (const float*)d_in[6];
  const float* b2    = (const float*)d_in[7];

  float* qxyz  = (float*)d_out;                       // [64][256][3]
  float* embed = qxyz + (size_t)B_BATCH * NQ * 3;     // [64][256][256]

  unsigned long long* gslot = (unsigned long long*)d_ws;

  // clear sync slots every launch (deterministic across graph replays)
  hipMemsetAsync(d_ws, 0, WS_CLEAR_BYTES, stream);

  hipLaunchKernelGGL(fps_kernel, dim3(B_BATCH * NBLK), dim3(FPS_T), 0, stream,
                     xyz, qxyz, gslot);
  hipLaunchKernelGGL(embed_mlp_kernel, dim3(B_BATCH * 4), dim3(512), 0, stream,
                     qxyz, pcmin, pcmax, G, W1, b1, W2, b2, embed);
}

// Round 19
// 569.456 us; speedup vs baseline: 19.4494x; 1.0295x over previous
//
#include <hip/hip_runtime.h>

#define FPS_N 32768
#define FPS_T 256          // threads per block
#define NBLK 8             // blocks per batch
#define PPB (FPS_N / NBLK) // 4096 points per block
#define PPT (PPB / FPS_T)  // 16 points per thread
#define NCH (PPT / 4)      // 4 four-point chunks per thread
#define NQ 256
#define DD 256
#define NT 64              // n-tile for MLP kernel
#define B_BATCH 64

// d_ws: u64 slot[64][256][8] = 1 MB, zeroed per launch
#define WS_CLEAR_BYTES (B_BATCH * NQ * NBLK * 8)

// ---------------------------------------------------------------------------
// Kernel 1: furthest point sampling — EXACT R12/R18 configuration (the
// empirical optimum: ~501us). R13-R17 attacked the ~1.7us/iter sync chain
// five ways; every variant regressed or was null (cross-block slots are
// serviced at the L3/IF coherence point; 255 serial rounds pay that RT).
// FROZEN — do not modify.
// ---------------------------------------------------------------------------
__global__ __attribute__((amdgpu_flat_work_group_size(FPS_T, FPS_T),
                          amdgpu_waves_per_eu(2, 2)))
void fps_kernel(const float* __restrict__ xyz, float* __restrict__ qout,
                unsigned long long* __restrict__ gslot) {
  const int gid = blockIdx.x;
  const int xcd = gid & 7;          // round-robin dispatch: block i -> XCD i%8
  const int s = gid >> 3;
  const int b = xcd + 8 * (s >> 3); // all 8 eighths of batch b on same XCD
  const int q = s & 7;
  const int t = threadIdx.x;

  const float* __restrict__ base = xyz + (size_t)b * (FPS_N * 3);
  const float4* __restrict__ base4 =
      (const float4*)(base + (size_t)q * PPB * 3) + (size_t)t * (PPT * 3 / 4);
  float* qb = qout + (size_t)b * (NQ * 3);
  unsigned long long* bslot = gslot + (size_t)b * (NQ * NBLK);

  __shared__ unsigned long long sred[FPS_T / 64];
  __shared__ float4 bc;   // broadcast: cx, cy, cz

  // persistent registers: coords 12 float4 = 48 VGPR, dist 4 float4 = 16 VGPR
  float4 C[PPT * 3 / 4];
#pragma unroll
  for (int i = 0; i < PPT * 3 / 4; ++i) C[i] = base4[i];
#pragma unroll
  for (int i = 0; i < PPT * 3 / 4; ++i) {   // pin: forbid remat
    asm volatile("" : "+v"(C[i].x), "+v"(C[i].y), "+v"(C[i].z), "+v"(C[i].w));
  }
  float4 Dst[NCH];
#pragma unroll
  for (int c = 0; c < NCH; ++c) Dst[c] = make_float4(1e10f, 1e10f, 1e10f, 1e10f);

  if (q == 0 && t == 0) { qb[0] = base[0]; qb[1] = base[1]; qb[2] = base[2]; }
  float cx = base[0], cy = base[1], cz = base[2];   // inds[0] == 0

#pragma unroll 1
  for (int j = 1; j < NQ; ++j) {
    float best = -1.0f;
    int bik = 0;

#pragma unroll
    for (int c = 0; c < NCH; ++c) {
      const float4 a4 = C[3 * c + 0];
      const float4 b4 = C[3 * c + 1];
      const float4 c4 = C[3 * c + 2];
      // unpack 12 floats -> 4 points (register renaming, no real ops)
      const float px[4] = {a4.x, a4.w, b4.z, c4.y};
      const float py[4] = {a4.y, b4.x, b4.w, c4.z};
      const float pz[4] = {a4.z, b4.y, c4.x, c4.w};
      const float dold[4] = {Dst[c].x, Dst[c].y, Dst[c].z, Dst[c].w};
      float dnew[4];
#pragma unroll
      for (int i = 0; i < 4; ++i) {
        const float dx = __fsub_rn(px[i], cx);
        const float dy = __fsub_rn(py[i], cy);
        const float dz = __fsub_rn(pz[i], cz);
        // numpy order: (dx^2 + dy^2) + dz^2, no fma
        const float d = __fadd_rn(__fadd_rn(__fmul_rn(dx, dx), __fmul_rn(dy, dy)),
                                  __fmul_rn(dz, dz));
        const float nd = fminf(dold[i], d);
        dnew[i] = nd;
        if (nd > best) { best = nd; bik = c * 4 + i; }  // strict >: first occ.
      }
      Dst[c] = make_float4(dnew[0], dnew[1], dnew[2], dnew[3]);
    }
    int bi = q * PPB + t * PPT + bik;   // global point index

    // wave (64-lane) argmax reduce with first-index tie-break
#pragma unroll
    for (int off = 32; off; off >>= 1) {
      const float ov = __shfl_xor(best, off);
      const int oi = __shfl_xor(bi, off);
      if (ov > best || (ov == best && oi < bi)) { best = ov; bi = oi; }
    }
    // pack: monotone in dist (f32>=0), ~idx -> max picks smallest index
    if ((t & 63) == 0) {
      sred[t >> 6] = ((unsigned long long)(unsigned int)__float_as_int(best) << 32) |
                     (unsigned int)~(unsigned int)bi;
    }
    __syncthreads();

    if (t < 64) {   // wave 0 handles block combine + cross-block sync
      unsigned long long p = sred[t & 3];
#pragma unroll
      for (int off = 1; off < 4; off <<= 1) {
        const unsigned long long o = __shfl_xor(p, off);
        if (o > p) p = o;
      }
      // p = this block's pack (identical in lanes 0-7)
      if (t == 0) {
        __hip_atomic_store(&bslot[j * NBLK + q], p, __ATOMIC_RELAXED,
                           __HIP_MEMORY_SCOPE_AGENT);
      }
      unsigned long long rp = 0;
      if (t < NBLK) {
        const unsigned long long* sl = &bslot[j * NBLK + t];
        do {
          rp = __hip_atomic_load(sl, __ATOMIC_RELAXED, __HIP_MEMORY_SCOPE_AGENT);
        } while (rp == 0ull);
      }
#pragma unroll
      for (int off = 1; off < NBLK; off <<= 1) {
        const unsigned long long o = __shfl_xor(rp, off);
        if (o > rp) rp = o;
      }
      if (t == 0) {
        const int gi = (int)~(unsigned int)(rp & 0xffffffffull);
        const float* cp = base + 3 * (size_t)gi;
        const float ncx = cp[0], ncy = cp[1], ncz = cp[2];
        bc = make_float4(ncx, ncy, ncz, 0.f);
        if (q == 0) { qb[3 * j + 0] = ncx; qb[3 * j + 1] = ncy; qb[3 * j + 2] = ncz; }
      }
    }
    __syncthreads();
    cx = bc.x; cy = bc.y; cz = bc.z;
  }
}

// ---------------------------------------------------------------------------
// Kernel 2: fourier positional embedding + 2-layer MLP, fused.
// R18 lesson: the 64 per-kt staging barriers were the cost (512-thr made it
// worse). This version stages NO W in LDS: W1/W2 (512KB) are L2-resident
// (read by all 256 blocks); each thread streams its 4 W rows directly from
// L2 as float4 (per wave: 4 distinct ty -> broadcast loads). P/H in LDS
// (140KB). THREE barriers total (snorm, P-fill, layer boundary) vs 67.
// Inner loop: pure FMA (16 indep accumulators) + loads -> FMA-issue-bound
// ~13.5us at 1 wave/SIMD.
// ---------------------------------------------------------------------------
__global__ __launch_bounds__(256) void embed_mlp_kernel(
    const float* __restrict__ qxyz, const float* __restrict__ pcmin,
    const float* __restrict__ pcmax, const float* __restrict__ G,
    const float* __restrict__ W1, const float* __restrict__ b1,
    const float* __restrict__ W2, const float* __restrict__ b2,
    float* __restrict__ out) {
  const int b = blockIdx.x >> 2;
  const int n0 = (blockIdx.x & 3) * NT;
  const int tid = threadIdx.x;
  const int ty = tid >> 4, tx = tid & 15;   // thread: d rows ty*4+i, n cols tx*4+k

  __shared__ __align__(16) float P[DD][NT + 4];   // pos (69632 B)
  __shared__ __align__(16) float H[DD][NT + 4];   // hidden (69632 B)
  __shared__ float snorm[NT][3];

  if (tid < NT) {
    const int n = n0 + tid;
    const float qx = qxyz[(size_t)b * (NQ * 3) + 3 * n + 0];
    const float qy = qxyz[(size_t)b * (NQ * 3) + 3 * n + 1];
    const float qz = qxyz[(size_t)b * (NQ * 3) + 3 * n + 2];
    snorm[tid][0] = (qx - pcmin[3 * b + 0]) / (pcmax[3 * b + 0] - pcmin[3 * b + 0]);
    snorm[tid][1] = (qy - pcmin[3 * b + 1]) / (pcmax[3 * b + 1] - pcmin[3 * b + 1]);
    snorm[tid][2] = (qz - pcmin[3 * b + 2]) / (pcmax[3 * b + 2] - pcmin[3 * b + 2]);
  }
  __syncthreads();

  {
    const int nn = tid & 63;
    const int fg = tid >> 6;   // 0..3
    const float nx = snorm[nn][0], ny = snorm[nn][1], nz = snorm[nn][2];
#pragma unroll 4
    for (int ff = 0; ff < 32; ++ff) {
      const int f = fg * 32 + ff;
      const float s = nx * G[f] + ny * G[128 + f] + nz * G[256 + f];
      const float proj = 6.28318530717958647692f * s;
      P[f][nn] = sinf(proj);
      P[f + 128][nn] = cosf(proj);
    }
  }
  __syncthreads();   // P complete

  for (int layer = 0; layer < 2; ++layer) {
    const float* W = layer ? W2 : W1;
    const float* bias = layer ? b2 : b1;
    const float (*src)[NT + 4] = layer ? H : P;
    if (layer) __syncthreads();   // H complete before layer 2 reads

    for (int dt = 0; dt < 4; ++dt) {
      float acc[4][4] = {};
      const float* wr0 = W + (size_t)(dt * 64 + ty * 4 + 0) * DD;
      const float* wr1 = wr0 + DD;
      const float* wr2 = wr1 + DD;
      const float* wr3 = wr2 + DD;
#pragma unroll 2
      for (int c = 0; c < DD; c += 4) {
        const float4 a0 = *(const float4*)(wr0 + c);
        const float4 a1 = *(const float4*)(wr1 + c);
        const float4 a2 = *(const float4*)(wr2 + c);
        const float4 a3 = *(const float4*)(wr3 + c);
        const float4 p0 = *(const float4*)&src[c + 0][tx * 4];
        const float4 p1 = *(const float4*)&src[c + 1][tx * 4];
        const float4 p2 = *(const float4*)&src[c + 2][tx * 4];
        const float4 p3 = *(const float4*)&src[c + 3][tx * 4];
        const float av[4][4] = {{a0.x, a0.y, a0.z, a0.w},
                                {a1.x, a1.y, a1.z, a1.w},
                                {a2.x, a2.y, a2.z, a2.w},
                                {a3.x, a3.y, a3.z, a3.w}};
        const float pv[4][4] = {{p0.x, p0.y, p0.z, p0.w},
                                {p1.x, p1.y, p1.z, p1.w},
                                {p2.x, p2.y, p2.z, p2.w},
                                {p3.x, p3.y, p3.z, p3.w}};
#pragma unroll
        for (int cj = 0; cj < 4; ++cj)
#pragma unroll
          for (int i = 0; i < 4; ++i)
#pragma unroll
            for (int k = 0; k < 4; ++k)
              acc[i][k] = fmaf(av[i][cj], pv[cj][k], acc[i][k]);
      }
      if (layer == 0) {
#pragma unroll
        for (int i = 0; i < 4; ++i) {
          const float bv = bias[dt * 64 + ty * 4 + i];
          float4 h;
          h.x = fmaxf(acc[i][0] + bv, 0.f);
          h.y = fmaxf(acc[i][1] + bv, 0.f);
          h.z = fmaxf(acc[i][2] + bv, 0.f);
          h.w = fmaxf(acc[i][3] + bv, 0.f);
          *(float4*)&H[dt * 64 + ty * 4 + i][tx * 4] = h;
        }
      } else {
        float* ob = out + (size_t)b * (DD * NQ);
#pragma unroll
        for (int i = 0; i < 4; ++i) {
          const float bv = bias[dt * 64 + ty * 4 + i];
          float4 h;
          h.x = fmaxf(acc[i][0] + bv, 0.f);
          h.y = fmaxf(acc[i][1] + bv, 0.f);
          h.z = fmaxf(acc[i][2] + bv, 0.f);
          h.w = fmaxf(acc[i][3] + bv, 0.f);
          *(float4*)(ob + (size_t)(dt * 64 + ty * 4 + i) * NQ + n0 + tx * 4) = h;
        }
      }
    }
  }
}

extern "C" void kernel_launch(void* const* d_in, const int* in_sizes, int n_in,
                              void* d_out, int out_size, void* d_ws, size_t ws_size,
                              hipStream_t stream) {
  (void)in_sizes; (void)n_in; (void)ws_size; (void)out_size;
  const float* xyz   = (const float*)d_in[0];
  const float* pcmin = (const float*)d_in[1];
  const float* pcmax = (const float*)d_in[2];
  const float* G     = (const float*)d_in[3];
  const float* W1    = (const float*)d_in[4];
  const float* b1    = (const float*)d_in[5];
  const float* W2    = (const float*)d_in[6];
  const float* b2    = (const float*)d_in[7];

  float* qxyz  = (float*)d_out;                       // [64][256][3]
  float* embed = qxyz + (size_t)B_BATCH * NQ * 3;     // [64][256][256]

  unsigned long long* gslot = (unsigned long long*)d_ws;

  // clear sync slots every launch (deterministic across graph replays)
  hipMemsetAsync(d_ws, 0, WS_CLEAR_BYTES, stream);

  hipLaunchKernelGGL(fps_kernel, dim3(B_BATCH * NBLK), dim3(FPS_T), 0, stream,
                     xyz, qxyz, gslot);
  hipLaunchKernelGGL(embed_mlp_kernel, dim3(B_BATCH * 4), dim3(256), 0, stream,
                     qxyz, pcmin, pcmax, G, W1, b1, W2, b2, embed);
}